// Round 2
// baseline (709.212 us; speedup 1.0000x reference)
//
#include <hip/hip_runtime.h>
#include <hip/hip_bf16.h>
#include <math.h>

#define B_    4
#define N_    4096
#define DIM_  256
#define H_    8
#define DH_   64
#define P_    2
#define INNER_ 512
#define BN_   (B_ * N_)      // 16384 rows for q/out
#define KVR_  (2 * BN_)      // 32768 rows for k/v

// ---------------------------------------------------------------------------
// Fold LN gamma/beta into projection weights:
//   W2[k][n] = g[k] * W[k][n];   b2[n] = (bias_in ? bias_in[n] : 0) + sum_k beta[k]*W[k][n]
// one block per output column n
// ---------------------------------------------------------------------------
__global__ void prep_weights(const float* __restrict__ W, const float* __restrict__ g,
                             const float* __restrict__ beta, const float* __restrict__ bias_in,
                             float* __restrict__ W2, float* __restrict__ b2, int K, int N) {
    int n = blockIdx.x;
    int t = threadIdx.x;
    float partial = 0.f;
    for (int k = t; k < K; k += 256) {
        float w = W[k * N + n];
        W2[k * N + n] = g[k] * w;
        partial += beta[k] * w;
    }
    __shared__ float red[256];
    red[t] = partial;
    __syncthreads();
    for (int s = 128; s > 0; s >>= 1) {
        if (t < s) red[t] += red[t + s];
        __syncthreads();
    }
    if (t == 0) b2[n] = (bias_in ? bias_in[n] : 0.f) + red[0];
}

// ---------------------------------------------------------------------------
// Per-row sum / sumsq over 256-wide rows of x (rows 0..16383) and prev_x
// (rows 16384..32767). One wave per row, float4 loads.
// ---------------------------------------------------------------------------
__global__ void stats_kernel(const float* __restrict__ x, const float* __restrict__ p,
                             float* __restrict__ sums, float* __restrict__ ssqs) {
    int lane = threadIdx.x & 63;
    int wv   = threadIdx.x >> 6;
    int r    = blockIdx.x * 4 + wv;            // 0..32767
    const float* src = (r < BN_) ? (x + (size_t)r * DIM_) : (p + (size_t)(r - BN_) * DIM_);
    float4 v = ((const float4*)src)[lane];
    float s  = v.x + v.y + v.z + v.w;
    float q2 = v.x * v.x + v.y * v.y + v.z * v.z + v.w * v.w;
    for (int d = 1; d < 64; d <<= 1) {
        s  += __shfl_xor(s, d);
        q2 += __shfl_xor(q2, d);
    }
    if (lane == 0) { sums[r] = s; ssqs[r] = q2; }
}

// mean/rstd for kv rows (width 256) and q rows (width 512 = concat of x,prev rows)
__global__ void derive_stats(const float* __restrict__ sums, const float* __restrict__ ssqs,
                             float2* __restrict__ st_kv, float2* __restrict__ st_q) {
    int i = blockIdx.x * 256 + threadIdx.x;
    if (i < KVR_) {
        float mean = sums[i] * (1.f / 256.f);
        float var  = ssqs[i] * (1.f / 256.f) - mean * mean;
        st_kv[i] = make_float2(mean, rsqrtf(var + 1e-5f));
    }
    if (i < BN_) {
        float s  = sums[i] + sums[i + BN_];
        float q2 = ssqs[i] + ssqs[i + BN_];
        float mean = s * (1.f / 512.f);
        float var  = q2 * (1.f / 512.f) - mean * mean;
        st_q[i] = make_float2(mean, rsqrtf(var + 1e-5f));
    }
}

// ---------------------------------------------------------------------------
// Generic fp32 GEMM, C[M,N] = normA[M,K] @ B (+bias), 64x64 tile, BK=16,
// 256 threads, 4x4 microtile. OT = float or __hip_bfloat16 output.
// MODE 0: A plain [M,K].    (A2, stats unused)
// MODE 1: row m = concat(x[m,:256], prev[m,:256]) normalized by stats[m] (K=512)
// MODE 2: row m = (m<Mh ? x[m] : prev[m-Mh]) normalized by stats[m]      (K=256)
// BT: B is [N,K] row-major (C = A @ B^T), else [K,N].
// ---------------------------------------------------------------------------
template <int MODE, bool BT, typename OT>
__global__ __launch_bounds__(256) void gemm_f32(
    const float* __restrict__ A, const float* __restrict__ A2,
    const float2* __restrict__ stats,
    const float* __restrict__ Bm, const float* __restrict__ bias,
    OT* __restrict__ C, int M, int N, int K, int Mh) {
    __shared__ float As[16][68];   // [kk][m], pad 68 -> aligned b128 reads, no conflicts
    __shared__ float Bs[16][68];   // [kk][n]
    const int tid = threadIdx.x;
    const int tx = tid & 15, ty = tid >> 4;
    const int row0 = blockIdx.y * 64, col0 = blockIdx.x * 64;
    float acc[4][4] = {};

    for (int k0 = 0; k0 < K; k0 += 16) {
        // ---- A tile: 64 rows x 16 k ----
#pragma unroll
        for (int i = 0; i < 4; i++) {
            int t  = tid + i * 256;
            int m  = t >> 4, kk = t & 15;
            int gm = row0 + m, gk = k0 + kk;
            float v;
            if (MODE == 0) {
                v = A[gm * K + gk];
            } else if (MODE == 1) {
                v = (gk < DIM_) ? A[gm * DIM_ + gk] : A2[gm * DIM_ + gk - DIM_];
                float2 st = stats[gm];
                v = (v - st.x) * st.y;
            } else {
                v = (gm < Mh) ? A[gm * DIM_ + gk] : A2[(gm - Mh) * DIM_ + gk];
                float2 st = stats[gm];
                v = (v - st.x) * st.y;
            }
            As[kk][m] = v;
        }
        // ---- B tile: 16 k x 64 n ----
#pragma unroll
        for (int i = 0; i < 4; i++) {
            int t = tid + i * 256;
            if (BT) {
                int n = t >> 4, kk = t & 15;
                Bs[kk][n] = Bm[(col0 + n) * K + k0 + kk];
            } else {
                int kk = t >> 6, n = t & 63;
                Bs[kk][n] = Bm[(k0 + kk) * N + col0 + n];
            }
        }
        __syncthreads();
#pragma unroll
        for (int kk = 0; kk < 16; kk++) {
            float a[4], b[4];
#pragma unroll
            for (int i = 0; i < 4; i++) a[i] = As[kk][ty * 4 + i];
#pragma unroll
            for (int j = 0; j < 4; j++) b[j] = Bs[kk][tx * 4 + j];
#pragma unroll
            for (int i = 0; i < 4; i++)
#pragma unroll
                for (int j = 0; j < 4; j++) acc[i][j] += a[i] * b[j];
        }
        __syncthreads();
    }
#pragma unroll
    for (int i = 0; i < 4; i++) {
        int m = row0 + ty * 4 + i;
#pragma unroll
        for (int j = 0; j < 4; j++) {
            int n = col0 + tx * 4 + j;
            float r = acc[i][j] + (bias ? bias[n] : 0.f);
            C[m * N + n] = (OT)r;
        }
    }
}

// ---------------------------------------------------------------------------
// offsets = q @ Woff^T + boff  (16 outputs per row), plus sampling indices.
// One wave per row m=(b,n): lane = hp + 16*seg, 4 segs x 128 k each.
// Writes offsets output in (B,H,P,N) layout and idx in (B,H,N,P).
// ---------------------------------------------------------------------------
__global__ void offsets_kernel(const float* __restrict__ q, const float* __restrict__ Woff,
                               const float* __restrict__ boff,
                               float* __restrict__ out_off, int* __restrict__ idx) {
    int lane = threadIdx.x & 63;
    int wv   = threadIdx.x >> 6;
    int m    = blockIdx.x * 4 + wv;           // b*N + n
    int hp   = lane & 15, seg = lane >> 4;
    const float* qr = q + (size_t)m * INNER_ + seg * 128;
    const float* wr = Woff + (size_t)hp * INNER_ + seg * 128;
    float a0 = 0.f, a1 = 0.f, a2 = 0.f, a3 = 0.f;
#pragma unroll 8
    for (int i = 0; i < 128; i += 4) {
        a0 += qr[i] * wr[i];
        a1 += qr[i + 1] * wr[i + 1];
        a2 += qr[i + 2] * wr[i + 2];
        a3 += qr[i + 3] * wr[i + 3];
    }
    float acc = (a0 + a1) + (a2 + a3);
    acc += __shfl_xor(acc, 16);
    acc += __shfl_xor(acc, 32);
    if (lane < 16) {
        float off = acc + boff[hp];
        int b = m >> 12, n = m & (N_ - 1);
        int h = hp >> 1, p = hp & 1;
        out_off[(size_t)((b * H_ + h) * P_ + p) * N_ + n] = off;
        float f = fminf(fmaxf((float)n + off, 0.f), (float)(2 * N_ - 1));
        idx[((size_t)(b * H_ + h) * N_ + n) * P_ + p] = (int)f;  // trunc == floor (f>=0)
    }
}

// ---------------------------------------------------------------------------
// Attention: one wave per (b,h,n); 64 lanes <-> DH. Gathers bf16 k/v rows
// (128 B contiguous per wave), wave-reduce dots, softmax over P=2.
// ---------------------------------------------------------------------------
__global__ void attn_kernel(const float* __restrict__ q,
                            const __hip_bfloat16* __restrict__ kproj,
                            const __hip_bfloat16* __restrict__ vproj,
                            const int* __restrict__ idx,
                            float* __restrict__ attn_out) {
    int lane = threadIdx.x & 63;
    int wv   = threadIdx.x >> 6;
    int n = blockIdx.x * 4 + wv;
    int h = blockIdx.y, b = blockIdx.z;
    int m = b * N_ + n;
    float qv = q[(size_t)m * INNER_ + h * DH_ + lane] * 0.125f;  // DH^-0.5

    const int* ip = idx + ((size_t)(b * H_ + h) * N_ + n) * P_;
    int j0 = ip[0], j1 = ip[1];
    // kproj row = s*BN_ + b*N_ + (j - s*N_) = b*N_ + j + s*(BN_-N_)
    int r0 = b * N_ + j0 + ((j0 >= N_) ? (BN_ - N_) : 0);
    int r1 = b * N_ + j1 + ((j1 >= N_) ? (BN_ - N_) : 0);
    size_t o0 = (size_t)r0 * INNER_ + h * DH_ + lane;
    size_t o1 = (size_t)r1 * INNER_ + h * DH_ + lane;
    float k0v = __bfloat162float(kproj[o0]), k1v = __bfloat162float(kproj[o1]);
    float v0v = __bfloat162float(vproj[o0]), v1v = __bfloat162float(vproj[o1]);

    float s0 = qv * k0v, s1 = qv * k1v;
    for (int d = 1; d < 64; d <<= 1) {
        s0 += __shfl_xor(s0, d);
        s1 += __shfl_xor(s1, d);
    }
    float mx = fmaxf(s0, s1);
    float e0 = expf(s0 - mx), e1 = expf(s1 - mx);
    float inv = 1.f / (e0 + e1);
    attn_out[(size_t)m * INNER_ + h * DH_ + lane] = (e0 * v0v + e1 * v1v) * inv;
}

// ---------------------------------------------------------------------------
extern "C" void kernel_launch(void* const* d_in, const int* in_sizes, int n_in,
                              void* d_out, int out_size, void* d_ws, size_t ws_size,
                              hipStream_t stream) {
    (void)in_sizes; (void)n_in; (void)out_size; (void)ws_size;

    const float* x      = (const float*)d_in[0];
    const float* prevx  = (const float*)d_in[1];
    const float* ln_q_g = (const float*)d_in[2];
    const float* ln_q_b = (const float*)d_in[3];
    const float* ln_k_g = (const float*)d_in[4];
    const float* ln_k_b = (const float*)d_in[5];
    const float* ln_v_g = (const float*)d_in[6];
    const float* ln_v_b = (const float*)d_in[7];
    const float* Wq     = (const float*)d_in[8];
    const float* Wk     = (const float*)d_in[9];
    const float* bk     = (const float*)d_in[10];
    const float* Wv     = (const float*)d_in[11];
    const float* bv     = (const float*)d_in[12];
    const float* Woff   = (const float*)d_in[13];
    const float* boff   = (const float*)d_in[14];
    const float* Wout   = (const float*)d_in[15];
    const float* bout   = (const float*)d_in[16];

    float* ws = (float*)d_ws;
    float* qbuf  = ws;                        // 16384*512 f32           =  32 MB
    float* aobuf = qbuf  + 8388608;           // 16384*512 f32           =  32 MB
    __hip_bfloat16* kproj = (__hip_bfloat16*)(aobuf + 8388608);  // 32768*512 bf16 = 32 MB
    __hip_bfloat16* vproj = kproj + 16777216;                    // 32768*512 bf16 = 32 MB
    float* Wq2   = (float*)(vproj + 16777216);// 512*512
    float* bq2   = Wq2   + 262144;            // 512
    float* Wk2   = bq2   + 512;               // 256*512
    float* bk2   = Wk2   + 131072;            // 512
    float* Wv2   = bk2   + 512;               // 256*512
    float* bv2   = Wv2   + 131072;            // 512
    float* sums  = bv2   + 512;               // 32768
    float* ssqs  = sums  + 32768;             // 32768
    float2* st_q  = (float2*)(ssqs + 32768);  // 16384
    float2* st_kv = st_q + 16384;             // 32768
    int*    idxb  = (int*)(st_kv + 32768);    // 262144
    // total ws: ~138 MB

    float* out_main = (float*)d_out;          // (B,N,DIM) = 4194304
    float* out_off  = out_main + (size_t)BN_ * DIM_;  // (B,H,P,N) = 262144

    // 1) fold LN affine into weights
    prep_weights<<<512, 256, 0, stream>>>(Wq, ln_q_g, ln_q_b, nullptr, Wq2, bq2, 512, 512);
    prep_weights<<<512, 256, 0, stream>>>(Wk, ln_k_g, ln_k_b, bk, Wk2, bk2, 256, 512);
    prep_weights<<<512, 256, 0, stream>>>(Wv, ln_v_g, ln_v_b, bv, Wv2, bv2, 256, 512);

    // 2) LN row statistics (single pass over x, prev_x)
    stats_kernel<<<KVR_ / 4, 256, 0, stream>>>(x, prevx, sums, ssqs);
    derive_stats<<<KVR_ / 256, 256, 0, stream>>>(sums, ssqs, st_kv, st_q);

    // 3) q projection (fp32 — index-critical path)
    dim3 gq(INNER_ / 64, BN_ / 64);
    gemm_f32<1, false, float><<<gq, 256, 0, stream>>>(x, prevx, st_q, Wq2, bq2, qbuf,
                                                      BN_, INNER_, 512, 0);

    // 4) offsets + sampling indices
    offsets_kernel<<<BN_ / 4, 256, 0, stream>>>(qbuf, Woff, boff, out_off, idxb);

    // 5) k / v projections (bf16 outputs)
    dim3 gkv(INNER_ / 64, KVR_ / 64);
    gemm_f32<2, false, __hip_bfloat16><<<gkv, 256, 0, stream>>>(x, prevx, st_kv, Wk2, bk2,
                                                                kproj, KVR_, INNER_, 256, BN_);
    gemm_f32<2, false, __hip_bfloat16><<<gkv, 256, 0, stream>>>(x, prevx, st_kv, Wv2, bv2,
                                                                vproj, KVR_, INNER_, 256, BN_);

    // 6) gather + softmax(P=2) + weighted sum
    dim3 ga(N_ / 4, H_, B_);
    attn_kernel<<<ga, 256, 0, stream>>>(qbuf, kproj, vproj, idxb, aobuf);

    // 7) output projection (C = A @ Wout^T + bout)
    dim3 go(DIM_ / 64, BN_ / 64);
    gemm_f32<0, true, float><<<go, 256, 0, stream>>>(aobuf, nullptr, nullptr, Wout, bout,
                                                     out_main, BN_, DIM_, 512, 0);
}

// Round 4
// 305.015 us; speedup vs baseline: 2.3252x; 2.3252x over previous
//
#include <hip/hip_runtime.h>
#include <hip/hip_bf16.h>
#include <math.h>

#define B_    4
#define N_    4096
#define DIM_  256
#define H_    8
#define DH_   64
#define P_    2
#define INNER_ 512
#define BN_   (B_ * N_)      // 16384 rows for q/out
#define KVR_  (2 * BN_)      // 32768 rows for k/v

typedef short v8s  __attribute__((ext_vector_type(8)));
typedef short v4s  __attribute__((ext_vector_type(4)));
typedef float v4f  __attribute__((ext_vector_type(4)));

__device__ __forceinline__ short f2b(float x) {
    __hip_bfloat16 h = __float2bfloat16(x);
    return *reinterpret_cast<short*>(&h);
}
__device__ __forceinline__ float b2f(short s) {
    __hip_bfloat16 h = *reinterpret_cast<__hip_bfloat16*>(&s);
    return __bfloat162float(h);
}

__device__ __forceinline__ void storeC(float* p, float v) { *p = v; }
__device__ __forceinline__ void storeC(__hip_bfloat16* p, float v) { *p = __float2bfloat16(v); }

// ---------------------------------------------------------------------------
// Fold LN gamma into W, transpose to [N][K] bf16; beta folded into fp32 bias.
// block per output column n; W is [K][N] fp32.
// ---------------------------------------------------------------------------
__global__ void prep_t(const float* __restrict__ W, const float* __restrict__ g,
                       const float* __restrict__ beta, const float* __restrict__ bias_in,
                       short* __restrict__ Wt, float* __restrict__ b2, int K, int N) {
    int n = blockIdx.x, t = threadIdx.x;
    float partial = 0.f;
    for (int k = t; k < K; k += 256) {
        float w = W[k * N + n];
        Wt[(size_t)n * K + k] = f2b(g[k] * w);
        partial += beta[k] * w;
    }
    __shared__ float red[256];
    red[t] = partial;
    __syncthreads();
    for (int s = 128; s > 0; s >>= 1) {
        if (t < s) red[t] += red[t + s];
        __syncthreads();
    }
    if (t == 0) b2[n] = (bias_in ? bias_in[n] : 0.f) + red[0];
}

// plain fp32 -> bf16 bits cast (for Wout, already [N][K] layout)
__global__ void cast_bf16(const float* __restrict__ src, short* __restrict__ dst, int n) {
    int i = blockIdx.x * 256 + threadIdx.x;
    if (i < n) dst[i] = f2b(src[i]);
}

// ---------------------------------------------------------------------------
// Wcomb[k][hp] = gq[k] * sum_j Wq[k][j] * Woff[hp][j]   (fp32, 512 x 16)
// ---------------------------------------------------------------------------
__global__ void wcomb_kernel(const float* __restrict__ Wq, const float* __restrict__ gq,
                             const float* __restrict__ Woff, float* __restrict__ Wcomb) {
    int k = blockIdx.x, t = threadIdx.x;
    int hp = t & 15, jg = t >> 4;
    float p = 0.f;
    for (int j = jg; j < INNER_; j += 16)
        p += Wq[k * INNER_ + j] * Woff[hp * INNER_ + j];
    __shared__ float red[16][17];
    red[jg][hp] = p;
    __syncthreads();
    if (t < 16) {
        float s = 0.f;
        for (int i = 0; i < 16; i++) s += red[i][t];
        Wcomb[k * 16 + t] = gq[k] * s;
    }
}

// bcomb[hp] = sum_j bq2[j]*Woff[hp][j] + boff[hp]   (bq2 = beta_q @ Wq)
__global__ void bcomb_kernel(const float* __restrict__ bq2, const float* __restrict__ Woff,
                             const float* __restrict__ boff, float* __restrict__ bcomb) {
    int t = threadIdx.x;
    int hp = t & 15, jg = t >> 4;
    float p = 0.f;
    for (int j = jg; j < INNER_; j += 16)
        p += bq2[j] * Woff[hp * INNER_ + j];
    __shared__ float red[16][17];
    red[jg][hp] = p;
    __syncthreads();
    if (t < 16) {
        float s = 0.f;
        for (int i = 0; i < 16; i++) s += red[i][t];
        bcomb[t] = s + boff[t];
    }
}

// ---------------------------------------------------------------------------
// Fused LN-stats + normalize for kv rows -> bf16 A matrix [KVR_][256].
// Wave per row; each lane holds 4 floats; shuffle-reduce sum/sumsq in-wave.
// ---------------------------------------------------------------------------
__global__ void normkv_kernel(const float* __restrict__ x, const float* __restrict__ p,
                              short* __restrict__ Akv) {
    int lane = threadIdx.x & 63;
    int wv   = threadIdx.x >> 6;
    int r    = blockIdx.x * 4 + wv;
    const float* src = (r < BN_) ? (x + (size_t)r * DIM_) : (p + (size_t)(r - BN_) * DIM_);
    float4 u = ((const float4*)src)[lane];
    float s  = u.x + u.y + u.z + u.w;
    float q2 = u.x * u.x + u.y * u.y + u.z * u.z + u.w * u.w;
    for (int d = 1; d < 64; d <<= 1) {
        s  += __shfl_xor(s, d);
        q2 += __shfl_xor(q2, d);
    }
    float mean = s * (1.f / 256.f);
    float var  = q2 * (1.f / 256.f) - mean * mean;
    float rstd = rsqrtf(var + 1e-5f);
    v4s o;
    o[0] = f2b((u.x - mean) * rstd);
    o[1] = f2b((u.y - mean) * rstd);
    o[2] = f2b((u.z - mean) * rstd);
    o[3] = f2b((u.w - mean) * rstd);
    *(v4s*)(Akv + (size_t)r * DIM_ + lane * 4) = o;
}

// ---------------------------------------------------------------------------
// Fused LN-stats + normalize q-concat rows -> bf16 A_q [BN_][512], AND fp32
// offsets (via composed Wcomb) + sampling indices. Wave per row m; 8 floats/lane.
// ---------------------------------------------------------------------------
__global__ void normq_off_kernel(const float* __restrict__ x, const float* __restrict__ p,
                                 const float* __restrict__ Wcomb, const float* __restrict__ bcomb,
                                 short* __restrict__ Aq, float* __restrict__ out_off,
                                 int* __restrict__ idx) {
    int lane = threadIdx.x & 63;
    int wv   = threadIdx.x >> 6;
    int m    = blockIdx.x * 4 + wv;
    int k8 = lane * 8;
    const float* src = (k8 < DIM_) ? (x + (size_t)m * DIM_ + k8)
                                   : (p + (size_t)m * DIM_ + k8 - DIM_);
    float4 u0 = ((const float4*)src)[0];
    float4 u1 = ((const float4*)src)[1];
    float s  = (u0.x + u0.y + u0.z + u0.w) + (u1.x + u1.y + u1.z + u1.w);
    float q2 = (u0.x * u0.x + u0.y * u0.y + u0.z * u0.z + u0.w * u0.w) +
               (u1.x * u1.x + u1.y * u1.y + u1.z * u1.z + u1.w * u1.w);
    for (int d = 1; d < 64; d <<= 1) {
        s  += __shfl_xor(s, d);
        q2 += __shfl_xor(q2, d);
    }
    float mean = s * (1.f / 512.f);
    float var  = q2 * (1.f / 512.f) - mean * mean;
    float rstd = rsqrtf(var + 1e-5f);

    float nv[8] = { (u0.x - mean) * rstd, (u0.y - mean) * rstd,
                    (u0.z - mean) * rstd, (u0.w - mean) * rstd,
                    (u1.x - mean) * rstd, (u1.y - mean) * rstd,
                    (u1.z - mean) * rstd, (u1.w - mean) * rstd };
    v8s ob;
#pragma unroll
    for (int i = 0; i < 8; i++) ob[i] = f2b(nv[i]);
    *(v8s*)(Aq + (size_t)m * INNER_ + k8) = ob;

    float acc[16];
#pragma unroll
    for (int h = 0; h < 16; h++) acc[h] = 0.f;
#pragma unroll
    for (int i = 0; i < 8; i++) {
        const float4* wr = (const float4*)(Wcomb + (size_t)(k8 + i) * 16);
        float4 w0 = wr[0], w1 = wr[1], w2 = wr[2], w3 = wr[3];
        float nvi = nv[i];
        acc[0]  += nvi * w0.x;  acc[1]  += nvi * w0.y;  acc[2]  += nvi * w0.z;  acc[3]  += nvi * w0.w;
        acc[4]  += nvi * w1.x;  acc[5]  += nvi * w1.y;  acc[6]  += nvi * w1.z;  acc[7]  += nvi * w1.w;
        acc[8]  += nvi * w2.x;  acc[9]  += nvi * w2.y;  acc[10] += nvi * w2.z;  acc[11] += nvi * w2.w;
        acc[12] += nvi * w3.x;  acc[13] += nvi * w3.y;  acc[14] += nvi * w3.z;  acc[15] += nvi * w3.w;
    }
    for (int d = 1; d < 64; d <<= 1) {
#pragma unroll
        for (int h = 0; h < 16; h++) acc[h] += __shfl_xor(acc[h], d);
    }
    if (lane < 16) {
        float off = acc[lane] + bcomb[lane];
        int b = m >> 12, n = m & (N_ - 1);
        int h = lane >> 1, pp = lane & 1;
        out_off[(size_t)((b * H_ + h) * P_ + pp) * N_ + n] = off;
        float f = fminf(fmaxf((float)n + off, 0.f), (float)(2 * N_ - 1));
        idx[((size_t)(b * H_ + h) * N_ + n) * P_ + pp] = (int)f;
    }
}

// ---------------------------------------------------------------------------
// bf16 MFMA GEMM: C[M][N] = A[M][K] @ Bt[N][K]^T + bias.
// 128x128 tile, BK=32, 256 thr = 4 waves (2x2), 4x4 frags of 16x16x32 / wave.
// Staging: register (global dwordx4) -> ds_write_b128, XOR chunk swizzle
// (kc ^= row&3) -> uniform bank distribution on the b128 fragment reads.
// ---------------------------------------------------------------------------
template <typename OT>
__global__ __launch_bounds__(256) void gemm_mfma(
    const short* __restrict__ A, const short* __restrict__ Bt,
    const float* __restrict__ bias, OT* __restrict__ C, int M, int N, int K) {
    __shared__ short As[128 * 32];
    __shared__ short Bs[128 * 32];
    const int tid  = threadIdx.x;
    const int lane = tid & 63, w = tid >> 6;
    const int wr = w >> 1, wc = w & 1;
    const int row0 = blockIdx.y * 128, col0 = blockIdx.x * 128;
    const int lm = lane & 15, g = lane >> 4;

    v4f acc[4][4];
#pragma unroll
    for (int i = 0; i < 4; i++)
#pragma unroll
        for (int j = 0; j < 4; j++) acc[i][j] = (v4f){0.f, 0.f, 0.f, 0.f};

    // chunk indices this thread stages (chunk = 8 shorts = 16 B)
    const int c0 = tid, c1 = tid + 256;
    const int tr0 = c0 >> 2, kg0 = (c0 & 3) ^ (tr0 & 3);
    const int tr1 = c1 >> 2, kg1 = (c1 & 3) ^ (tr1 & 3);

    for (int k0 = 0; k0 < K; k0 += 32) {
        v8s ra0 = *(const v8s*)(A  + (size_t)(row0 + tr0) * K + k0 + kg0 * 8);
        v8s ra1 = *(const v8s*)(A  + (size_t)(row0 + tr1) * K + k0 + kg1 * 8);
        v8s rb0 = *(const v8s*)(Bt + (size_t)(col0 + tr0) * K + k0 + kg0 * 8);
        v8s rb1 = *(const v8s*)(Bt + (size_t)(col0 + tr1) * K + k0 + kg1 * 8);
        __syncthreads();   // previous iteration's fragment reads complete
        *(v8s*)(As + c0 * 8) = ra0;
        *(v8s*)(As + c1 * 8) = ra1;
        *(v8s*)(Bs + c0 * 8) = rb0;
        *(v8s*)(Bs + c1 * 8) = rb1;
        __syncthreads();

        v8s af[4], bf[4];
#pragma unroll
        for (int i = 0; i < 4; i++) {
            int m  = wr * 64 + i * 16 + lm;
            int ch = m * 4 + (g ^ (m & 3));
            af[i] = *(const v8s*)(As + ch * 8);
        }
#pragma unroll
        for (int j = 0; j < 4; j++) {
            int n  = wc * 64 + j * 16 + lm;
            int ch = n * 4 + (g ^ (n & 3));
            bf[j] = *(const v8s*)(Bs + ch * 8);
        }
#pragma unroll
        for (int i = 0; i < 4; i++)
#pragma unroll
            for (int j = 0; j < 4; j++)
                acc[i][j] = __builtin_amdgcn_mfma_f32_16x16x32_bf16(af[i], bf[j], acc[i][j], 0, 0, 0);
    }

    // epilogue: C/D layout col=lane&15, row=(lane>>4)*4+reg
#pragma unroll
    for (int j = 0; j < 4; j++) {
        int gc = col0 + wc * 64 + j * 16 + lm;
        float bj = bias ? bias[gc] : 0.f;
#pragma unroll
        for (int i = 0; i < 4; i++) {
            int gr = row0 + wr * 64 + i * 16 + g * 4;
#pragma unroll
            for (int r = 0; r < 4; r++)
                storeC(&C[(size_t)(gr + r) * N + gc], acc[i][j][r] + bj);
        }
    }
}

// ---------------------------------------------------------------------------
// Attention: wave per (b,h,n). kvproj layout [row][1024]: k cols 0-511, v 512+.
// ---------------------------------------------------------------------------
__global__ void attn_kernel(const short* __restrict__ qb, const short* __restrict__ kvproj,
                            const int* __restrict__ idx, short* __restrict__ attnout) {
    int lane = threadIdx.x & 63;
    int wv   = threadIdx.x >> 6;
    int n = blockIdx.x * 4 + wv;
    int h = blockIdx.y, b = blockIdx.z;
    int m = b * N_ + n;
    float qv = b2f(qb[(size_t)m * INNER_ + h * DH_ + lane]) * 0.125f;

    const int* ip = idx + ((size_t)(b * H_ + h) * N_ + n) * P_;
    int j0 = ip[0], j1 = ip[1];
    int r0 = b * N_ + j0 + ((j0 >= N_) ? (BN_ - N_) : 0);
    int r1 = b * N_ + j1 + ((j1 >= N_) ? (BN_ - N_) : 0);
    size_t o0 = (size_t)r0 * 1024 + h * DH_ + lane;
    size_t o1 = (size_t)r1 * 1024 + h * DH_ + lane;
    float k0v = b2f(kvproj[o0]),       k1v = b2f(kvproj[o1]);
    float v0v = b2f(kvproj[o0 + 512]), v1v = b2f(kvproj[o1 + 512]);

    float s0 = qv * k0v, s1 = qv * k1v;
    for (int d = 1; d < 64; d <<= 1) {
        s0 += __shfl_xor(s0, d);
        s1 += __shfl_xor(s1, d);
    }
    float mx = fmaxf(s0, s1);
    float e0 = expf(s0 - mx), e1 = expf(s1 - mx);
    float inv = 1.f / (e0 + e1);
    attnout[(size_t)m * INNER_ + h * DH_ + lane] = f2b((e0 * v0v + e1 * v1v) * inv);
}

// ---------------------------------------------------------------------------
extern "C" void kernel_launch(void* const* d_in, const int* in_sizes, int n_in,
                              void* d_out, int out_size, void* d_ws, size_t ws_size,
                              hipStream_t stream) {
    (void)in_sizes; (void)n_in; (void)out_size; (void)ws_size;

    const float* x      = (const float*)d_in[0];
    const float* prevx  = (const float*)d_in[1];
    const float* ln_q_g = (const float*)d_in[2];
    const float* ln_q_b = (const float*)d_in[3];
    const float* ln_k_g = (const float*)d_in[4];
    const float* ln_k_b = (const float*)d_in[5];
    const float* ln_v_g = (const float*)d_in[6];
    const float* ln_v_b = (const float*)d_in[7];
    const float* Wq     = (const float*)d_in[8];
    const float* Wk     = (const float*)d_in[9];
    const float* bk     = (const float*)d_in[10];
    const float* Wv     = (const float*)d_in[11];
    const float* bv     = (const float*)d_in[12];
    const float* Woff   = (const float*)d_in[13];
    const float* boff   = (const float*)d_in[14];
    const float* Wout   = (const float*)d_in[15];
    const float* bout   = (const float*)d_in[16];

    char* cur = (char*)d_ws;
    auto alloc = [&](size_t bytes) { char* p = cur; cur += (bytes + 255) & ~(size_t)255; return p; };
    short* Aq      = (short*)alloc((size_t)BN_ * INNER_ * 2);     // 16 MB
    short* Akv     = (short*)alloc((size_t)KVR_ * DIM_ * 2);      // 16 MB
    short* qb      = (short*)alloc((size_t)BN_ * INNER_ * 2);     // 16 MB
    short* kvproj  = (short*)alloc((size_t)KVR_ * 1024 * 2);      // 64 MB
    short* attnout = (short*)alloc((size_t)BN_ * INNER_ * 2);     // 16 MB
    short* Wq2t    = (short*)alloc(512 * 512 * 2);
    short* Wkvt    = (short*)alloc(1024 * 256 * 2);
    short* Woutb   = (short*)alloc(256 * 512 * 2);
    float* bq2     = (float*)alloc(512 * 4);
    float* bkv     = (float*)alloc(1024 * 4);
    float* Wcomb   = (float*)alloc(512 * 16 * 4);
    float* bcomb   = (float*)alloc(16 * 4);
    int*   idxb    = (int*)alloc((size_t)BN_ * 16 * 4);
    // total ~130 MB

    float* out_main = (float*)d_out;                      // (B,N,DIM)
    float* out_off  = out_main + (size_t)BN_ * DIM_;      // (B,H,P,N)

    // 1) weight prep (transposed bf16, LN-folded) + composed offset weights
    prep_t<<<512, 256, 0, stream>>>(Wq, ln_q_g, ln_q_b, nullptr, Wq2t, bq2, 512, 512);
    prep_t<<<512, 256, 0, stream>>>(Wk, ln_k_g, ln_k_b, bk, Wkvt, bkv, 256, 512);
    prep_t<<<512, 256, 0, stream>>>(Wv, ln_v_g, ln_v_b, bv, Wkvt + 512 * 256, bkv + 512, 256, 512);
    cast_bf16<<<512, 256, 0, stream>>>(Wout, Woutb, 256 * 512);
    wcomb_kernel<<<512, 256, 0, stream>>>(Wq, ln_q_g, Woff, Wcomb);
    bcomb_kernel<<<1, 256, 0, stream>>>(bq2, Woff, boff, bcomb);

    // 2) fused LN + bf16 activations; q-path also emits fp32 offsets + indices
    normkv_kernel<<<KVR_ / 4, 256, 0, stream>>>(x, prevx, Akv);
    normq_off_kernel<<<BN_ / 4, 256, 0, stream>>>(x, prevx, Wcomb, bcomb,
                                                  Aq, out_off, idxb);

    // 3) MFMA GEMMs
    gemm_mfma<__hip_bfloat16><<<dim3(INNER_ / 128, BN_ / 128), 256, 0, stream>>>(
        Aq, Wq2t, bq2, (__hip_bfloat16*)qb, BN_, INNER_, 512);
    gemm_mfma<__hip_bfloat16><<<dim3(1024 / 128, KVR_ / 128), 256, 0, stream>>>(
        Akv, Wkvt, bkv, (__hip_bfloat16*)kvproj, KVR_, 1024, 256);

    // 4) gather + softmax(P=2) + weighted sum
    dim3 ga(N_ / 4, H_, B_);
    attn_kernel<<<ga, 256, 0, stream>>>(qb, kvproj, idxb, attnout);

    // 5) output projection
    gemm_mfma<float><<<dim3(DIM_ / 128, BN_ / 128), 256, 0, stream>>>(
        attnout, Woutb, bout, out_main, BN_, DIM_, 512);
}

// Round 6
// 296.611 us; speedup vs baseline: 2.3910x; 1.0283x over previous
//
#include <hip/hip_runtime.h>
#include <hip/hip_bf16.h>
#include <math.h>

#define B_    4
#define N_    4096
#define DIM_  256
#define H_    8
#define DH_   64
#define P_    2
#define INNER_ 512
#define BN_   (B_ * N_)      // 16384 rows for q/out
#define KVR_  (2 * BN_)      // 32768 rows for k/v

typedef short v8s  __attribute__((ext_vector_type(8)));
typedef short v4s  __attribute__((ext_vector_type(4)));
typedef float v4f  __attribute__((ext_vector_type(4)));

__device__ __forceinline__ short f2b(float x) {
    __hip_bfloat16 h = __float2bfloat16(x);
    return *reinterpret_cast<short*>(&h);
}
__device__ __forceinline__ float b2f(short s) {
    __hip_bfloat16 h = *reinterpret_cast<__hip_bfloat16*>(&s);
    return __bfloat162float(h);
}

__device__ __forceinline__ void storeC(float* p, float v) { *p = v; }
__device__ __forceinline__ void storeC(__hip_bfloat16* p, float v) { *p = __float2bfloat16(v); }

// ---------------------------------------------------------------------------
// Fold LN gamma into W, transpose to [N][K] bf16; beta folded into fp32 bias.
// ---------------------------------------------------------------------------
__global__ void prep_t(const float* __restrict__ W, const float* __restrict__ g,
                       const float* __restrict__ beta, const float* __restrict__ bias_in,
                       short* __restrict__ Wt, float* __restrict__ b2, int K, int N) {
    int n = blockIdx.x, t = threadIdx.x;
    float partial = 0.f;
    for (int k = t; k < K; k += 256) {
        float w = W[k * N + n];
        Wt[(size_t)n * K + k] = f2b(g[k] * w);
        partial += beta[k] * w;
    }
    __shared__ float red[256];
    red[t] = partial;
    __syncthreads();
    for (int s = 128; s > 0; s >>= 1) {
        if (t < s) red[t] += red[t + s];
        __syncthreads();
    }
    if (t == 0) b2[n] = (bias_in ? bias_in[n] : 0.f) + red[0];
}

__global__ void cast_bf16(const float* __restrict__ src, short* __restrict__ dst, int n) {
    int i = blockIdx.x * 256 + threadIdx.x;
    if (i < n) dst[i] = f2b(src[i]);
}

// ---------------------------------------------------------------------------
// Wcomb[k][hp] = gq[k] * sum_j Wq[k][j] * Woff[hp][j]   (fp32, 512 x 16)
// ---------------------------------------------------------------------------
__global__ void wcomb_kernel(const float* __restrict__ Wq, const float* __restrict__ gq,
                             const float* __restrict__ Woff, float* __restrict__ Wcomb) {
    int k = blockIdx.x, t = threadIdx.x;
    int hp = t & 15, jg = t >> 4;
    float p = 0.f;
    for (int j = jg; j < INNER_; j += 16)
        p += Wq[k * INNER_ + j] * Woff[hp * INNER_ + j];
    __shared__ float red[16][17];
    red[jg][hp] = p;
    __syncthreads();
    if (t < 16) {
        float s = 0.f;
        for (int i = 0; i < 16; i++) s += red[i][t];
        Wcomb[k * 16 + t] = gq[k] * s;
    }
}

// bcomb[hp] = sum_j bq2[j]*Woff[hp][j] + boff[hp]   (bq2 = beta_q @ Wq)
__global__ void bcomb_kernel(const float* __restrict__ bq2, const float* __restrict__ Woff,
                             const float* __restrict__ boff, float* __restrict__ bcomb) {
    int t = threadIdx.x;
    int hp = t & 15, jg = t >> 4;
    float p = 0.f;
    for (int j = jg; j < INNER_; j += 16)
        p += bq2[j] * Woff[hp * INNER_ + j];
    __shared__ float red[16][17];
    red[jg][hp] = p;
    __syncthreads();
    if (t < 16) {
        float s = 0.f;
        for (int i = 0; i < 16; i++) s += red[i][t];
        bcomb[t] = s + boff[t];
    }
}

// ---------------------------------------------------------------------------
// FUSED single-pass kernel. One wave per m:
//   lanes 0-31  hold x[m][lane*8 .. +7], lanes 32-63 hold prev[m][..].
//   5 butterfly rounds  -> per-half sums  = kv LN stats (256-wide)
//   +1 round            -> full sums      = q  LN stats (512-wide)
//   writes Akv rows m / BN_+m (bf16), Aq row m (bf16),
//   offsets via Wcomb in fp32 (split-butterfly reduction: 32 shuffles), idx.
// ---------------------------------------------------------------------------
__global__ __launch_bounds__(256) void norm_fused_kernel(
    const float* __restrict__ x, const float* __restrict__ p,
    const float* __restrict__ Wcomb, const float* __restrict__ bcomb,
    short* __restrict__ Aq, short* __restrict__ Akv,
    float* __restrict__ out_off, int* __restrict__ idx) {
    int lane = threadIdx.x & 63;
    int wv   = threadIdx.x >> 6;
    int m    = blockIdx.x * 4 + wv;
    int k8   = lane * 8;
    const float* src = (lane < 32) ? (x + (size_t)m * DIM_ + k8)
                                   : (p + (size_t)m * DIM_ + k8 - DIM_);
    float4 u0 = ((const float4*)src)[0];
    float4 u1 = ((const float4*)src)[1];
    float uv[8] = { u0.x, u0.y, u0.z, u0.w, u1.x, u1.y, u1.z, u1.w };

    float s = 0.f, q2 = 0.f;
#pragma unroll
    for (int i = 0; i < 8; i++) { s += uv[i]; q2 += uv[i] * uv[i]; }
    // 5 rounds: per-half (32-lane / 256-elem) sums
#pragma unroll
    for (int d = 1; d <= 16; d <<= 1) {
        s  += __shfl_xor(s, d);
        q2 += __shfl_xor(q2, d);
    }
    float mean_h = s * (1.f / 256.f);
    float var_h  = q2 * (1.f / 256.f) - mean_h * mean_h;
    float rstd_h = rsqrtf(var_h + 1e-5f);
    // 6th round: full 512-wide q stats
    float sf  = s  + __shfl_xor(s, 32);
    float q2f = q2 + __shfl_xor(q2, 32);
    float mean_q = sf * (1.f / 512.f);
    float var_q  = q2f * (1.f / 512.f) - mean_q * mean_q;
    float rstd_q = rsqrtf(var_q + 1e-5f);

    // kv write (per-half stats)
    v8s okv;
#pragma unroll
    for (int i = 0; i < 8; i++) okv[i] = f2b((uv[i] - mean_h) * rstd_h);
    short* akvdst = Akv + ((lane < 32) ? ((size_t)m * DIM_ + k8)
                                       : ((size_t)(BN_ + m) * DIM_ + k8 - DIM_));
    *(v8s*)akvdst = okv;

    // q write (full stats) + keep fp32 normalized values for offsets
    float nv[8];
    v8s oq;
#pragma unroll
    for (int i = 0; i < 8; i++) { nv[i] = (uv[i] - mean_q) * rstd_q; oq[i] = f2b(nv[i]); }
    *(v8s*)(Aq + (size_t)m * INNER_ + k8) = oq;

    // offsets: acc[h] = sum_k nv[k] * Wcomb[k][h]
    float acc[16];
#pragma unroll
    for (int h = 0; h < 16; h++) acc[h] = 0.f;
#pragma unroll
    for (int i = 0; i < 8; i++) {
        const float4* wr = (const float4*)(Wcomb + (size_t)(k8 + i) * 16);
        float4 w0 = wr[0], w1 = wr[1], w2 = wr[2], w3 = wr[3];
        float nvi = uv[0]; // dummy init to keep structure; replaced below
        nvi = nv[i];
        acc[0]  += nvi * w0.x;  acc[1]  += nvi * w0.y;  acc[2]  += nvi * w0.z;  acc[3]  += nvi * w0.w;
        acc[4]  += nvi * w1.x;  acc[5]  += nvi * w1.y;  acc[6]  += nvi * w1.z;  acc[7]  += nvi * w1.w;
        acc[8]  += nvi * w2.x;  acc[9]  += nvi * w2.y;  acc[10] += nvi * w2.z;  acc[11] += nvi * w2.w;
        acc[12] += nvi * w3.x;  acc[13] += nvi * w3.y;  acc[14] += nvi * w3.z;  acc[15] += nvi * w3.w;
    }
    // split-butterfly: halve acc vector each round (32 shuffles total).
    // Invariant: after the round with distance d, lane l holds partials for
    // output h with (h & (2d-1)) == (l & (2d-1)), summed over the 2d-lane coset.
    float a8[8];
#pragma unroll
    for (int j = 0; j < 8; j++) {
        float lo = acc[2 * j] + __shfl_xor(acc[2 * j], 1);
        float hi = acc[2 * j + 1] + __shfl_xor(acc[2 * j + 1], 1);
        a8[j] = (lane & 1) ? hi : lo;
    }
    float a4[4];
#pragma unroll
    for (int j = 0; j < 4; j++) {
        float lo = a8[2 * j] + __shfl_xor(a8[2 * j], 2);
        float hi = a8[2 * j + 1] + __shfl_xor(a8[2 * j + 1], 2);
        a4[j] = (lane & 2) ? hi : lo;
    }
    float a2[2];
#pragma unroll
    for (int j = 0; j < 2; j++) {
        float lo = a4[2 * j] + __shfl_xor(a4[2 * j], 4);
        float hi = a4[2 * j + 1] + __shfl_xor(a4[2 * j + 1], 4);
        a2[j] = (lane & 4) ? hi : lo;
    }
    float l1 = a2[0] + __shfl_xor(a2[0], 8);
    float h1 = a2[1] + __shfl_xor(a2[1], 8);
    float a1 = (lane & 8) ? h1 : l1;      // holds output h = lane & 15, partial over 16 lanes
    a1 += __shfl_xor(a1, 16);
    a1 += __shfl_xor(a1, 32);             // full 64-lane sum

    if (lane < 16) {
        float off = a1 + bcomb[lane];
        int b = m >> 12, n = m & (N_ - 1);
        int h = lane >> 1, pp = lane & 1;
        out_off[(size_t)((b * H_ + h) * P_ + pp) * N_ + n] = off;
        float f = fminf(fmaxf((float)n + off, 0.f), (float)(2 * N_ - 1));
        idx[((size_t)(b * H_ + h) * N_ + n) * P_ + pp] = (int)f;
    }
}

// ---------------------------------------------------------------------------
// bf16 MFMA GEMM: C[M][N] = A[M][K] @ Bt[N][K]^T + bias.
// 128x128 tile, BK=32, 256 thr = 4 waves (2x2), 4x4 frags of 16x16x32 / wave.
// Staging: register (global dwordx4) -> ds_write_b128, XOR chunk swizzle.
// ---------------------------------------------------------------------------
template <typename OT>
__global__ __launch_bounds__(256) void gemm_mfma(
    const short* __restrict__ A, const short* __restrict__ Bt,
    const float* __restrict__ bias, OT* __restrict__ C, int M, int N, int K) {
    __shared__ short As[128 * 32];
    __shared__ short Bs[128 * 32];
    const int tid  = threadIdx.x;
    const int lane = tid & 63, w = tid >> 6;
    const int wr = w >> 1, wc = w & 1;
    const int row0 = blockIdx.y * 128, col0 = blockIdx.x * 128;
    const int lm = lane & 15, g = lane >> 4;

    v4f acc[4][4];
#pragma unroll
    for (int i = 0; i < 4; i++)
#pragma unroll
        for (int j = 0; j < 4; j++) acc[i][j] = (v4f){0.f, 0.f, 0.f, 0.f};

    const int c0 = tid, c1 = tid + 256;
    const int tr0 = c0 >> 2, kg0 = (c0 & 3) ^ (tr0 & 3);
    const int tr1 = c1 >> 2, kg1 = (c1 & 3) ^ (tr1 & 3);

    for (int k0 = 0; k0 < K; k0 += 32) {
        v8s ra0 = *(const v8s*)(A  + (size_t)(row0 + tr0) * K + k0 + kg0 * 8);
        v8s ra1 = *(const v8s*)(A  + (size_t)(row0 + tr1) * K + k0 + kg1 * 8);
        v8s rb0 = *(const v8s*)(Bt + (size_t)(col0 + tr0) * K + k0 + kg0 * 8);
        v8s rb1 = *(const v8s*)(Bt + (size_t)(col0 + tr1) * K + k0 + kg1 * 8);
        __syncthreads();
        *(v8s*)(As + c0 * 8) = ra0;
        *(v8s*)(As + c1 * 8) = ra1;
        *(v8s*)(Bs + c0 * 8) = rb0;
        *(v8s*)(Bs + c1 * 8) = rb1;
        __syncthreads();

        v8s af[4], bf[4];
#pragma unroll
        for (int i = 0; i < 4; i++) {
            int m  = wr * 64 + i * 16 + lm;
            int ch = m * 4 + (g ^ (m & 3));
            af[i] = *(const v8s*)(As + ch * 8);
        }
#pragma unroll
        for (int j = 0; j < 4; j++) {
            int n  = wc * 64 + j * 16 + lm;
            int ch = n * 4 + (g ^ (n & 3));
            bf[j] = *(const v8s*)(Bs + ch * 8);
        }
#pragma unroll
        for (int i = 0; i < 4; i++)
#pragma unroll
            for (int j = 0; j < 4; j++)
                acc[i][j] = __builtin_amdgcn_mfma_f32_16x16x32_bf16(af[i], bf[j], acc[i][j], 0, 0, 0);
    }

#pragma unroll
    for (int j = 0; j < 4; j++) {
        int gc = col0 + wc * 64 + j * 16 + lm;
        float bj = bias ? bias[gc] : 0.f;
#pragma unroll
        for (int i = 0; i < 4; i++) {
            int gr = row0 + wr * 64 + i * 16 + g * 4;
#pragma unroll
            for (int r = 0; r < 4; r++)
                storeC(&C[(size_t)(gr + r) * N + gc], acc[i][j][r] + bj);
        }
    }
}

// ---------------------------------------------------------------------------
// Attention: wave per (b,h,n). kvproj layout [row][1024]: k cols 0-511, v 512+.
// ---------------------------------------------------------------------------
__global__ void attn_kernel(const short* __restrict__ qb, const short* __restrict__ kvproj,
                            const int* __restrict__ idx, short* __restrict__ attnout) {
    int lane = threadIdx.x & 63;
    int wv   = threadIdx.x >> 6;
    int n = blockIdx.x * 4 + wv;
    int h = blockIdx.y, b = blockIdx.z;
    int m = b * N_ + n;
    float qv = b2f(qb[(size_t)m * INNER_ + h * DH_ + lane]) * 0.125f;

    const int* ip = idx + ((size_t)(b * H_ + h) * N_ + n) * P_;
    int j0 = ip[0], j1 = ip[1];
    int r0 = b * N_ + j0 + ((j0 >= N_) ? (BN_ - N_) : 0);
    int r1 = b * N_ + j1 + ((j1 >= N_) ? (BN_ - N_) : 0);
    size_t o0 = (size_t)r0 * 1024 + h * DH_ + lane;
    size_t o1 = (size_t)r1 * 1024 + h * DH_ + lane;
    float k0v = b2f(kvproj[o0]),       k1v = b2f(kvproj[o1]);
    float v0v = b2f(kvproj[o0 + 512]), v1v = b2f(kvproj[o1 + 512]);

    float s0 = qv * k0v, s1 = qv * k1v;
    for (int d = 1; d < 64; d <<= 1) {
        s0 += __shfl_xor(s0, d);
        s1 += __shfl_xor(s1, d);
    }
    float mx = fmaxf(s0, s1);
    float e0 = expf(s0 - mx), e1 = expf(s1 - mx);
    float inv = 1.f / (e0 + e1);
    attnout[(size_t)m * INNER_ + h * DH_ + lane] = f2b((e0 * v0v + e1 * v1v) * inv);
}

// ---------------------------------------------------------------------------
extern "C" void kernel_launch(void* const* d_in, const int* in_sizes, int n_in,
                              void* d_out, int out_size, void* d_ws, size_t ws_size,
                              hipStream_t stream) {
    (void)in_sizes; (void)n_in; (void)out_size; (void)ws_size;

    const float* x      = (const float*)d_in[0];
    const float* prevx  = (const float*)d_in[1];
    const float* ln_q_g = (const float*)d_in[2];
    const float* ln_q_b = (const float*)d_in[3];
    const float* ln_k_g = (const float*)d_in[4];
    const float* ln_k_b = (const float*)d_in[5];
    const float* ln_v_g = (const float*)d_in[6];
    const float* ln_v_b = (const float*)d_in[7];
    const float* Wq     = (const float*)d_in[8];
    const float* Wk     = (const float*)d_in[9];
    const float* bk     = (const float*)d_in[10];
    const float* Wv     = (const float*)d_in[11];
    const float* bv     = (const float*)d_in[12];
    const float* Woff   = (const float*)d_in[13];
    const float* boff   = (const float*)d_in[14];
    const float* Wout   = (const float*)d_in[15];
    const float* bout   = (const float*)d_in[16];

    char* cur = (char*)d_ws;
    auto alloc = [&](size_t bytes) { char* p = cur; cur += (bytes + 255) & ~(size_t)255; return p; };
    short* Aq      = (short*)alloc((size_t)BN_ * INNER_ * 2);     // 16 MB
    short* Akv     = (short*)alloc((size_t)KVR_ * DIM_ * 2);      // 16 MB
    short* qb      = (short*)alloc((size_t)BN_ * INNER_ * 2);     // 16 MB
    short* kvproj  = (short*)alloc((size_t)KVR_ * 1024 * 2);      // 64 MB
    short* attnout = (short*)alloc((size_t)BN_ * INNER_ * 2);     // 16 MB
    short* Wq2t    = (short*)alloc(512 * 512 * 2);
    short* Wkvt    = (short*)alloc(1024 * 256 * 2);
    short* Woutb   = (short*)alloc(256 * 512 * 2);
    float* bq2     = (float*)alloc(512 * 4);
    float* bkv     = (float*)alloc(1024 * 4);
    float* Wcomb   = (float*)alloc(512 * 16 * 4);
    float* bcomb   = (float*)alloc(16 * 4);
    int*   idxb    = (int*)alloc((size_t)BN_ * 16 * 4);
    // total ~130 MB

    float* out_main = (float*)d_out;                      // (B,N,DIM)
    float* out_off  = out_main + (size_t)BN_ * DIM_;      // (B,H,P,N)

    // 1) weight prep (transposed bf16, LN-folded) + composed offset weights
    prep_t<<<512, 256, 0, stream>>>(Wq, ln_q_g, ln_q_b, nullptr, Wq2t, bq2, 512, 512);
    prep_t<<<512, 256, 0, stream>>>(Wk, ln_k_g, ln_k_b, bk, Wkvt, bkv, 256, 512);
    prep_t<<<512, 256, 0, stream>>>(Wv, ln_v_g, ln_v_b, bv, Wkvt + 512 * 256, bkv + 512, 256, 512);
    cast_bf16<<<512, 256, 0, stream>>>(Wout, Woutb, 256 * 512);
    wcomb_kernel<<<512, 256, 0, stream>>>(Wq, ln_q_g, Woff, Wcomb);
    bcomb_kernel<<<1, 256, 0, stream>>>(bq2, Woff, boff, bcomb);

    // 2) single-pass fused LN + activations + offsets + indices
    norm_fused_kernel<<<BN_ / 4, 256, 0, stream>>>(x, prevx, Wcomb, bcomb,
                                                   Aq, Akv, out_off, idxb);

    // 3) MFMA GEMMs
    gemm_mfma<__hip_bfloat16><<<dim3(INNER_ / 128, BN_ / 128), 256, 0, stream>>>(
        Aq, Wq2t, bq2, (__hip_bfloat16*)qb, BN_, INNER_, 512);
    gemm_mfma<__hip_bfloat16><<<dim3(1024 / 128, KVR_ / 128), 256, 0, stream>>>(
        Akv, Wkvt, bkv, (__hip_bfloat16*)kvproj, KVR_, 1024, 256);

    // 4) gather + softmax(P=2) + weighted sum
    dim3 ga(N_ / 4, H_, B_);
    attn_kernel<<<ga, 256, 0, stream>>>(qb, kvproj, idxb, attnout);

    // 5) output projection
    gemm_mfma<float><<<dim3(DIM_ / 128, BN_ / 128), 256, 0, stream>>>(
        attnout, Woutb, bout, out_main, BN_, DIM_, 512);
}

// Round 7
// 256.594 us; speedup vs baseline: 2.7639x; 1.1560x over previous
//
#include <hip/hip_runtime.h>
#include <hip/hip_bf16.h>
#include <math.h>

#define B_    4
#define N_    4096
#define DIM_  256
#define H_    8
#define DH_   64
#define P_    2
#define INNER_ 512
#define BN_   (B_ * N_)      // 16384 rows for q/out
#define KVR_  (2 * BN_)      // 32768 rows for k/v

typedef short v8s  __attribute__((ext_vector_type(8)));
typedef short v4s  __attribute__((ext_vector_type(4)));
typedef float v4f  __attribute__((ext_vector_type(4)));

__device__ __forceinline__ short f2b(float x) {
    __hip_bfloat16 h = __float2bfloat16(x);
    return *reinterpret_cast<short*>(&h);
}
__device__ __forceinline__ float b2f(short s) {
    __hip_bfloat16 h = *reinterpret_cast<__hip_bfloat16*>(&s);
    return __bfloat162float(h);
}

__device__ __forceinline__ void storeC(float* p, float v) { *p = v; }
__device__ __forceinline__ void storeC(__hip_bfloat16* p, float v) { *p = __float2bfloat16(v); }

// ---------------------------------------------------------------------------
// Fold LN gamma into W, transpose to [N][K] bf16; beta folded into fp32 bias.
// ---------------------------------------------------------------------------
__global__ void prep_t(const float* __restrict__ W, const float* __restrict__ g,
                       const float* __restrict__ beta, const float* __restrict__ bias_in,
                       short* __restrict__ Wt, float* __restrict__ b2, int K, int N) {
    int n = blockIdx.x, t = threadIdx.x;
    float partial = 0.f;
    for (int k = t; k < K; k += 256) {
        float w = W[k * N + n];
        Wt[(size_t)n * K + k] = f2b(g[k] * w);
        partial += beta[k] * w;
    }
    __shared__ float red[256];
    red[t] = partial;
    __syncthreads();
    for (int s = 128; s > 0; s >>= 1) {
        if (t < s) red[t] += red[t + s];
        __syncthreads();
    }
    if (t == 0) b2[n] = (bias_in ? bias_in[n] : 0.f) + red[0];
}

__global__ void cast_bf16(const float* __restrict__ src, short* __restrict__ dst, int n) {
    int i = blockIdx.x * 256 + threadIdx.x;
    if (i < n) dst[i] = f2b(src[i]);
}

// ---------------------------------------------------------------------------
// Wcomb[k][hp] = gq[k] * sum_j Wq[k][j] * Woff[hp][j]   (fp32, 512 x 16)
// ---------------------------------------------------------------------------
__global__ void wcomb_kernel(const float* __restrict__ Wq, const float* __restrict__ gq,
                             const float* __restrict__ Woff, float* __restrict__ Wcomb) {
    int k = blockIdx.x, t = threadIdx.x;
    int hp = t & 15, jg = t >> 4;
    float p = 0.f;
    for (int j = jg; j < INNER_; j += 16)
        p += Wq[k * INNER_ + j] * Woff[hp * INNER_ + j];
    __shared__ float red[16][17];
    red[jg][hp] = p;
    __syncthreads();
    if (t < 16) {
        float s = 0.f;
        for (int i = 0; i < 16; i++) s += red[i][t];
        Wcomb[k * 16 + t] = gq[k] * s;
    }
}

// bcomb[hp] = sum_j bq2[j]*Woff[hp][j] + boff[hp]   (bq2 = beta_q @ Wq)
__global__ void bcomb_kernel(const float* __restrict__ bq2, const float* __restrict__ Woff,
                             const float* __restrict__ boff, float* __restrict__ bcomb) {
    int t = threadIdx.x;
    int hp = t & 15, jg = t >> 4;
    float p = 0.f;
    for (int j = jg; j < INNER_; j += 16)
        p += bq2[j] * Woff[hp * INNER_ + j];
    __shared__ float red[16][17];
    red[jg][hp] = p;
    __syncthreads();
    if (t < 16) {
        float s = 0.f;
        for (int i = 0; i < 16; i++) s += red[i][t];
        bcomb[t] = s + boff[t];
    }
}

// ---------------------------------------------------------------------------
// FUSED single-pass LN + activations + offsets. One wave per 4 rows.
// Lane l owns k-slice [8l,8l+8); its Wcomb slice (8 rows x 16 = 128 fp32)
// is row-invariant -> preloaded into VGPRs ONCE per wave. Per row: pure
// register FMA stream + butterfly reductions; next row's x/prev prefetched.
// ---------------------------------------------------------------------------
__global__ __launch_bounds__(256) void norm_fused_kernel(
    const float* __restrict__ x, const float* __restrict__ p,
    const float* __restrict__ Wcomb, const float* __restrict__ bcomb,
    short* __restrict__ Aq, short* __restrict__ Akv,
    float* __restrict__ out_off, int* __restrict__ idx) {
    const int lane = threadIdx.x & 63;
    const int wv   = threadIdx.x >> 6;
    const int m0   = (blockIdx.x * 4 + wv) * 4;   // first of 4 rows
    const int k8   = lane * 8;

    // preload Wcomb slice: w[i][j] = Wcomb[k8+i][4j..4j+3]
    float4 w[8][4];
#pragma unroll
    for (int i = 0; i < 8; i++) {
        const float4* wr = (const float4*)(Wcomb + (size_t)(k8 + i) * 16);
#pragma unroll
        for (int j = 0; j < 4; j++) w[i][j] = wr[j];
    }
    const float bc = bcomb[lane & 15];

    // per-lane source base (x half for lanes 0-31, prev half for 32-63)
    const float* srcb = (lane < 32) ? (x + k8) : (p + k8 - DIM_);

    float4 u0 = ((const float4*)(srcb + (size_t)m0 * DIM_))[0];
    float4 u1 = ((const float4*)(srcb + (size_t)m0 * DIM_))[1];

#pragma unroll
    for (int r = 0; r < 4; r++) {
        const int m = m0 + r;
        float4 n0, n1;
        if (r < 3) {   // prefetch next row
            n0 = ((const float4*)(srcb + (size_t)(m + 1) * DIM_))[0];
            n1 = ((const float4*)(srcb + (size_t)(m + 1) * DIM_))[1];
        }
        float uv[8] = { u0.x, u0.y, u0.z, u0.w, u1.x, u1.y, u1.z, u1.w };

        float s = 0.f, q2 = 0.f;
#pragma unroll
        for (int i = 0; i < 8; i++) { s += uv[i]; q2 += uv[i] * uv[i]; }
#pragma unroll
        for (int d = 1; d <= 16; d <<= 1) {
            s  += __shfl_xor(s, d);
            q2 += __shfl_xor(q2, d);
        }
        float mean_h = s * (1.f / 256.f);
        float var_h  = q2 * (1.f / 256.f) - mean_h * mean_h;
        float rstd_h = rsqrtf(var_h + 1e-5f);
        float sf  = s  + __shfl_xor(s, 32);
        float q2f = q2 + __shfl_xor(q2, 32);
        float mean_q = sf * (1.f / 512.f);
        float var_q  = q2f * (1.f / 512.f) - mean_q * mean_q;
        float rstd_q = rsqrtf(var_q + 1e-5f);

        // kv write (per-half stats)
        v8s okv;
#pragma unroll
        for (int i = 0; i < 8; i++) okv[i] = f2b((uv[i] - mean_h) * rstd_h);
        short* akvdst = Akv + ((lane < 32) ? ((size_t)m * DIM_ + k8)
                                           : ((size_t)(BN_ + m) * DIM_ + k8 - DIM_));
        *(v8s*)akvdst = okv;

        // q write (full stats) + fp32 normalized values for offsets
        float nv[8];
        v8s oq;
#pragma unroll
        for (int i = 0; i < 8; i++) { nv[i] = (uv[i] - mean_q) * rstd_q; oq[i] = f2b(nv[i]); }
        *(v8s*)(Aq + (size_t)m * INNER_ + k8) = oq;

        // offsets: acc[h] = sum_i nv[i] * w[i][h]  (register-resident weights)
        float acc[16];
#pragma unroll
        for (int h = 0; h < 16; h++) acc[h] = 0.f;
#pragma unroll
        for (int i = 0; i < 8; i++) {
            float nvi = nv[i];
            acc[0]  += nvi * w[i][0].x;  acc[1]  += nvi * w[i][0].y;
            acc[2]  += nvi * w[i][0].z;  acc[3]  += nvi * w[i][0].w;
            acc[4]  += nvi * w[i][1].x;  acc[5]  += nvi * w[i][1].y;
            acc[6]  += nvi * w[i][1].z;  acc[7]  += nvi * w[i][1].w;
            acc[8]  += nvi * w[i][2].x;  acc[9]  += nvi * w[i][2].y;
            acc[10] += nvi * w[i][2].z;  acc[11] += nvi * w[i][2].w;
            acc[12] += nvi * w[i][3].x;  acc[13] += nvi * w[i][3].y;
            acc[14] += nvi * w[i][3].z;  acc[15] += nvi * w[i][3].w;
        }
        // split-butterfly: halve acc vector each round (30 shuffles + 2)
        float a8[8];
#pragma unroll
        for (int j = 0; j < 8; j++) {
            float lo = acc[2 * j] + __shfl_xor(acc[2 * j], 1);
            float hi = acc[2 * j + 1] + __shfl_xor(acc[2 * j + 1], 1);
            a8[j] = (lane & 1) ? hi : lo;
        }
        float a4[4];
#pragma unroll
        for (int j = 0; j < 4; j++) {
            float lo = a8[2 * j] + __shfl_xor(a8[2 * j], 2);
            float hi = a8[2 * j + 1] + __shfl_xor(a8[2 * j + 1], 2);
            a4[j] = (lane & 2) ? hi : lo;
        }
        float a2[2];
#pragma unroll
        for (int j = 0; j < 2; j++) {
            float lo = a4[2 * j] + __shfl_xor(a4[2 * j], 4);
            float hi = a4[2 * j + 1] + __shfl_xor(a4[2 * j + 1], 4);
            a2[j] = (lane & 4) ? hi : lo;
        }
        float l1 = a2[0] + __shfl_xor(a2[0], 8);
        float h1 = a2[1] + __shfl_xor(a2[1], 8);
        float a1 = (lane & 8) ? h1 : l1;
        a1 += __shfl_xor(a1, 16);
        a1 += __shfl_xor(a1, 32);

        if (lane < 16) {
            float off = a1 + bc;
            int b = m >> 12, n = m & (N_ - 1);
            int h = lane >> 1, pp = lane & 1;
            out_off[(size_t)((b * H_ + h) * P_ + pp) * N_ + n] = off;
            float f = fminf(fmaxf((float)n + off, 0.f), (float)(2 * N_ - 1));
            idx[((size_t)(b * H_ + h) * N_ + n) * P_ + pp] = (int)f;
        }
        u0 = n0; u1 = n1;
    }
}

// ---------------------------------------------------------------------------
// bf16 MFMA GEMM: C[M][N] = A[M][K] @ Bt[N][K]^T + bias.
// 128x128 tile, BK=32, 256 thr = 4 waves (2x2), 4x4 frags of 16x16x32 / wave.
// Staging: register (global dwordx4) -> ds_write_b128, XOR chunk swizzle.
// ---------------------------------------------------------------------------
template <typename OT>
__global__ __launch_bounds__(256) void gemm_mfma(
    const short* __restrict__ A, const short* __restrict__ Bt,
    const float* __restrict__ bias, OT* __restrict__ C, int M, int N, int K) {
    __shared__ short As[128 * 32];
    __shared__ short Bs[128 * 32];
    const int tid  = threadIdx.x;
    const int lane = tid & 63, w = tid >> 6;
    const int wr = w >> 1, wc = w & 1;
    const int row0 = blockIdx.y * 128, col0 = blockIdx.x * 128;
    const int lm = lane & 15, g = lane >> 4;

    v4f acc[4][4];
#pragma unroll
    for (int i = 0; i < 4; i++)
#pragma unroll
        for (int j = 0; j < 4; j++) acc[i][j] = (v4f){0.f, 0.f, 0.f, 0.f};

    const int c0 = tid, c1 = tid + 256;
    const int tr0 = c0 >> 2, kg0 = (c0 & 3) ^ (tr0 & 3);
    const int tr1 = c1 >> 2, kg1 = (c1 & 3) ^ (tr1 & 3);

    for (int k0 = 0; k0 < K; k0 += 32) {
        v8s ra0 = *(const v8s*)(A  + (size_t)(row0 + tr0) * K + k0 + kg0 * 8);
        v8s ra1 = *(const v8s*)(A  + (size_t)(row0 + tr1) * K + k0 + kg1 * 8);
        v8s rb0 = *(const v8s*)(Bt + (size_t)(col0 + tr0) * K + k0 + kg0 * 8);
        v8s rb1 = *(const v8s*)(Bt + (size_t)(col0 + tr1) * K + k0 + kg1 * 8);
        __syncthreads();
        *(v8s*)(As + c0 * 8) = ra0;
        *(v8s*)(As + c1 * 8) = ra1;
        *(v8s*)(Bs + c0 * 8) = rb0;
        *(v8s*)(Bs + c1 * 8) = rb1;
        __syncthreads();

        v8s af[4], bf[4];
#pragma unroll
        for (int i = 0; i < 4; i++) {
            int m  = wr * 64 + i * 16 + lm;
            int ch = m * 4 + (g ^ (m & 3));
            af[i] = *(const v8s*)(As + ch * 8);
        }
#pragma unroll
        for (int j = 0; j < 4; j++) {
            int n  = wc * 64 + j * 16 + lm;
            int ch = n * 4 + (g ^ (n & 3));
            bf[j] = *(const v8s*)(Bs + ch * 8);
        }
#pragma unroll
        for (int i = 0; i < 4; i++)
#pragma unroll
            for (int j = 0; j < 4; j++)
                acc[i][j] = __builtin_amdgcn_mfma_f32_16x16x32_bf16(af[i], bf[j], acc[i][j], 0, 0, 0);
    }

#pragma unroll
    for (int j = 0; j < 4; j++) {
        int gc = col0 + wc * 64 + j * 16 + lm;
        float bj = bias ? bias[gc] : 0.f;
#pragma unroll
        for (int i = 0; i < 4; i++) {
            int gr = row0 + wr * 64 + i * 16 + g * 4;
#pragma unroll
            for (int r = 0; r < 4; r++)
                storeC(&C[(size_t)(gr + r) * N + gc], acc[i][j][r] + bj);
        }
    }
}

// ---------------------------------------------------------------------------
// Attention: wave per 2 samples (2-way ILP on the shuffle chains).
// kvproj layout [row][1024]: k cols 0-511, v 512+.
// ---------------------------------------------------------------------------
__global__ __launch_bounds__(256) void attn_kernel(
    const short* __restrict__ qb, const short* __restrict__ kvproj,
    const int* __restrict__ idx, short* __restrict__ attnout) {
    int lane = threadIdx.x & 63;
    int wv   = threadIdx.x >> 6;
    int n0 = blockIdx.x * 8 + wv * 2;
    int h = blockIdx.y, b = blockIdx.z;
    int mA = b * N_ + n0, mB = mA + 1;

    float qA = b2f(qb[(size_t)mA * INNER_ + h * DH_ + lane]) * 0.125f;
    float qB = b2f(qb[(size_t)mB * INNER_ + h * DH_ + lane]) * 0.125f;

    const int* ipA = idx + ((size_t)(b * H_ + h) * N_ + n0) * P_;
    int jA0 = ipA[0], jA1 = ipA[1], jB0 = ipA[2], jB1 = ipA[3];
    int rA0 = b * N_ + jA0 + ((jA0 >= N_) ? (BN_ - N_) : 0);
    int rA1 = b * N_ + jA1 + ((jA1 >= N_) ? (BN_ - N_) : 0);
    int rB0 = b * N_ + jB0 + ((jB0 >= N_) ? (BN_ - N_) : 0);
    int rB1 = b * N_ + jB1 + ((jB1 >= N_) ? (BN_ - N_) : 0);
    size_t oA0 = (size_t)rA0 * 1024 + h * DH_ + lane;
    size_t oA1 = (size_t)rA1 * 1024 + h * DH_ + lane;
    size_t oB0 = (size_t)rB0 * 1024 + h * DH_ + lane;
    size_t oB1 = (size_t)rB1 * 1024 + h * DH_ + lane;

    float kA0 = b2f(kvproj[oA0]),       kA1 = b2f(kvproj[oA1]);
    float kB0 = b2f(kvproj[oB0]),       kB1 = b2f(kvproj[oB1]);
    float vA0 = b2f(kvproj[oA0 + 512]), vA1 = b2f(kvproj[oA1 + 512]);
    float vB0 = b2f(kvproj[oB0 + 512]), vB1 = b2f(kvproj[oB1 + 512]);

    float sA0 = qA * kA0, sA1 = qA * kA1;
    float sB0 = qB * kB0, sB1 = qB * kB1;
    for (int d = 1; d < 64; d <<= 1) {
        sA0 += __shfl_xor(sA0, d);
        sA1 += __shfl_xor(sA1, d);
        sB0 += __shfl_xor(sB0, d);
        sB1 += __shfl_xor(sB1, d);
    }
    float mxA = fmaxf(sA0, sA1), mxB = fmaxf(sB0, sB1);
    float eA0 = __expf(sA0 - mxA), eA1 = __expf(sA1 - mxA);
    float eB0 = __expf(sB0 - mxB), eB1 = __expf(sB1 - mxB);
    float invA = 1.f / (eA0 + eA1), invB = 1.f / (eB0 + eB1);
    attnout[(size_t)mA * INNER_ + h * DH_ + lane] = f2b((eA0 * vA0 + eA1 * vA1) * invA);
    attnout[(size_t)mB * INNER_ + h * DH_ + lane] = f2b((eB0 * vB0 + eB1 * vB1) * invB);
}

// ---------------------------------------------------------------------------
extern "C" void kernel_launch(void* const* d_in, const int* in_sizes, int n_in,
                              void* d_out, int out_size, void* d_ws, size_t ws_size,
                              hipStream_t stream) {
    (void)in_sizes; (void)n_in; (void)out_size; (void)ws_size;

    const float* x      = (const float*)d_in[0];
    const float* prevx  = (const float*)d_in[1];
    const float* ln_q_g = (const float*)d_in[2];
    const float* ln_q_b = (const float*)d_in[3];
    const float* ln_k_g = (const float*)d_in[4];
    const float* ln_k_b = (const float*)d_in[5];
    const float* ln_v_g = (const float*)d_in[6];
    const float* ln_v_b = (const float*)d_in[7];
    const float* Wq     = (const float*)d_in[8];
    const float* Wk     = (const float*)d_in[9];
    const float* bk     = (const float*)d_in[10];
    const float* Wv     = (const float*)d_in[11];
    const float* bv     = (const float*)d_in[12];
    const float* Woff   = (const float*)d_in[13];
    const float* boff   = (const float*)d_in[14];
    const float* Wout   = (const float*)d_in[15];
    const float* bout   = (const float*)d_in[16];

    char* cur = (char*)d_ws;
    auto alloc = [&](size_t bytes) { char* p = cur; cur += (bytes + 255) & ~(size_t)255; return p; };
    short* Aq      = (short*)alloc((size_t)BN_ * INNER_ * 2);     // 16 MB
    short* Akv     = (short*)alloc((size_t)KVR_ * DIM_ * 2);      // 16 MB
    short* qb      = (short*)alloc((size_t)BN_ * INNER_ * 2);     // 16 MB
    short* kvproj  = (short*)alloc((size_t)KVR_ * 1024 * 2);      // 64 MB
    short* attnout = (short*)alloc((size_t)BN_ * INNER_ * 2);     // 16 MB
    short* Wq2t    = (short*)alloc(512 * 512 * 2);
    short* Wkvt    = (short*)alloc(1024 * 256 * 2);
    short* Woutb   = (short*)alloc(256 * 512 * 2);
    float* bq2     = (float*)alloc(512 * 4);
    float* bkv     = (float*)alloc(1024 * 4);
    float* Wcomb   = (float*)alloc(512 * 16 * 4);
    float* bcomb   = (float*)alloc(16 * 4);
    int*   idxb    = (int*)alloc((size_t)BN_ * 16 * 4);
    // total ~130 MB

    float* out_main = (float*)d_out;                      // (B,N,DIM)
    float* out_off  = out_main + (size_t)BN_ * DIM_;      // (B,H,P,N)

    // 1) weight prep (transposed bf16, LN-folded) + composed offset weights
    prep_t<<<512, 256, 0, stream>>>(Wq, ln_q_g, ln_q_b, nullptr, Wq2t, bq2, 512, 512);
    prep_t<<<512, 256, 0, stream>>>(Wk, ln_k_g, ln_k_b, bk, Wkvt, bkv, 256, 512);
    prep_t<<<512, 256, 0, stream>>>(Wv, ln_v_g, ln_v_b, bv, Wkvt + 512 * 256, bkv + 512, 256, 512);
    cast_bf16<<<512, 256, 0, stream>>>(Wout, Woutb, 256 * 512);
    wcomb_kernel<<<512, 256, 0, stream>>>(Wq, ln_q_g, Woff, Wcomb);
    bcomb_kernel<<<1, 256, 0, stream>>>(bq2, Woff, boff, bcomb);

    // 2) single-pass fused LN + activations + offsets + indices (4 rows/wave)
    norm_fused_kernel<<<BN_ / 16, 256, 0, stream>>>(x, prevx, Wcomb, bcomb,
                                                    Aq, Akv, out_off, idxb);

    // 3) MFMA GEMMs
    gemm_mfma<__hip_bfloat16><<<dim3(INNER_ / 128, BN_ / 128), 256, 0, stream>>>(
        Aq, Wq2t, bq2, (__hip_bfloat16*)qb, BN_, INNER_, 512);
    gemm_mfma<__hip_bfloat16><<<dim3(1024 / 128, KVR_ / 128), 256, 0, stream>>>(
        Akv, Wkvt, bkv, (__hip_bfloat16*)kvproj, KVR_, 1024, 256);

    // 4) gather + softmax(P=2) + weighted sum (2 samples per wave)
    dim3 ga(N_ / 8, H_, B_);
    attn_kernel<<<ga, 256, 0, stream>>>(qb, kvproj, idxb, attnout);

    // 5) output projection
    gemm_mfma<float><<<dim3(DIM_ / 128, BN_ / 128), 256, 0, stream>>>(
        attnout, Woutb, bout, out_main, BN_, DIM_, 512);
}

// Round 8
// 246.434 us; speedup vs baseline: 2.8779x; 1.0412x over previous
//
#include <hip/hip_runtime.h>
#include <hip/hip_bf16.h>
#include <math.h>

#define B_    4
#define N_    4096
#define DIM_  256
#define H_    8
#define DH_   64
#define P_    2
#define INNER_ 512
#define BN_   (B_ * N_)      // 16384 rows for q/out
#define KVR_  (2 * BN_)      // 32768 rows for k/v

typedef short v8s  __attribute__((ext_vector_type(8)));
typedef short v4s  __attribute__((ext_vector_type(4)));
typedef float v4f  __attribute__((ext_vector_type(4)));

__device__ __forceinline__ short f2b(float x) {
    __hip_bfloat16 h = __float2bfloat16(x);
    return *reinterpret_cast<short*>(&h);
}
__device__ __forceinline__ float b2f(short s) {
    __hip_bfloat16 h = *reinterpret_cast<__hip_bfloat16*>(&s);
    return __bfloat162float(h);
}

__device__ __forceinline__ void async16(const void* g, void* l) {
    __builtin_amdgcn_global_load_lds(
        (const __attribute__((address_space(1))) void*)g,
        (__attribute__((address_space(3))) void*)l, 16, 0, 0);
}

// 16 consecutive elements of one row -> wide stores
__device__ __forceinline__ void storeRow(float* p, float4 f0, float4 f1, float4 f2, float4 f3) {
    ((float4*)p)[0] = f0; ((float4*)p)[1] = f1; ((float4*)p)[2] = f2; ((float4*)p)[3] = f3;
}
__device__ __forceinline__ void storeRow(__hip_bfloat16* p, float4 f0, float4 f1, float4 f2, float4 f3) {
    v8s o0, o1;
    o0[0]=f2b(f0.x); o0[1]=f2b(f0.y); o0[2]=f2b(f0.z); o0[3]=f2b(f0.w);
    o0[4]=f2b(f1.x); o0[5]=f2b(f1.y); o0[6]=f2b(f1.z); o0[7]=f2b(f1.w);
    o1[0]=f2b(f2.x); o1[1]=f2b(f2.y); o1[2]=f2b(f2.z); o1[3]=f2b(f2.w);
    o1[4]=f2b(f3.x); o1[5]=f2b(f3.y); o1[6]=f2b(f3.z); o1[7]=f2b(f3.w);
    ((v8s*)p)[0] = o0; ((v8s*)p)[1] = o1;
}

// ---------------------------------------------------------------------------
// Fold LN gamma into W, transpose to [N][K] bf16; beta folded into fp32 bias.
// ---------------------------------------------------------------------------
__global__ void prep_t(const float* __restrict__ W, const float* __restrict__ g,
                       const float* __restrict__ beta, const float* __restrict__ bias_in,
                       short* __restrict__ Wt, float* __restrict__ b2, int K, int N) {
    int n = blockIdx.x, t = threadIdx.x;
    float partial = 0.f;
    for (int k = t; k < K; k += 256) {
        float w = W[k * N + n];
        Wt[(size_t)n * K + k] = f2b(g[k] * w);
        partial += beta[k] * w;
    }
    __shared__ float red[256];
    red[t] = partial;
    __syncthreads();
    for (int s = 128; s > 0; s >>= 1) {
        if (t < s) red[t] += red[t + s];
        __syncthreads();
    }
    if (t == 0) b2[n] = (bias_in ? bias_in[n] : 0.f) + red[0];
}

__global__ void cast_bf16(const float* __restrict__ src, short* __restrict__ dst, int n) {
    int i = blockIdx.x * 256 + threadIdx.x;
    if (i < n) dst[i] = f2b(src[i]);
}

// ---------------------------------------------------------------------------
// Wcomb[k][hp] = gq[k] * sum_j Wq[k][j] * Woff[hp][j]   (fp32, 512 x 16)
// ---------------------------------------------------------------------------
__global__ void wcomb_kernel(const float* __restrict__ Wq, const float* __restrict__ gq,
                             const float* __restrict__ Woff, float* __restrict__ Wcomb) {
    int k = blockIdx.x, t = threadIdx.x;
    int hp = t & 15, jg = t >> 4;
    float p = 0.f;
    for (int j = jg; j < INNER_; j += 16)
        p += Wq[k * INNER_ + j] * Woff[hp * INNER_ + j];
    __shared__ float red[16][17];
    red[jg][hp] = p;
    __syncthreads();
    if (t < 16) {
        float s = 0.f;
        for (int i = 0; i < 16; i++) s += red[i][t];
        Wcomb[k * 16 + t] = gq[k] * s;
    }
}

// bcomb[hp] = sum_j bq2[j]*Woff[hp][j] + boff[hp]   (bq2 = beta_q @ Wq)
__global__ void bcomb_kernel(const float* __restrict__ bq2, const float* __restrict__ Woff,
                             const float* __restrict__ boff, float* __restrict__ bcomb) {
    int t = threadIdx.x;
    int hp = t & 15, jg = t >> 4;
    float p = 0.f;
    for (int j = jg; j < INNER_; j += 16)
        p += bq2[j] * Woff[hp * INNER_ + j];
    __shared__ float red[16][17];
    red[jg][hp] = p;
    __syncthreads();
    if (t < 16) {
        float s = 0.f;
        for (int i = 0; i < 16; i++) s += red[i][t];
        bcomb[t] = s + boff[t];
    }
}

// ---------------------------------------------------------------------------
// FUSED single-pass LN + activations + offsets. One wave per 4 rows.
// Wcomb slice register-resident; per-row pure FMA + butterfly reductions.
// ---------------------------------------------------------------------------
__global__ __launch_bounds__(256) void norm_fused_kernel(
    const float* __restrict__ x, const float* __restrict__ p,
    const float* __restrict__ Wcomb, const float* __restrict__ bcomb,
    short* __restrict__ Aq, short* __restrict__ Akv,
    float* __restrict__ out_off, int* __restrict__ idx) {
    const int lane = threadIdx.x & 63;
    const int wv   = threadIdx.x >> 6;
    const int m0   = (blockIdx.x * 4 + wv) * 4;   // first of 4 rows
    const int k8   = lane * 8;

    float4 w[8][4];
#pragma unroll
    for (int i = 0; i < 8; i++) {
        const float4* wr = (const float4*)(Wcomb + (size_t)(k8 + i) * 16);
#pragma unroll
        for (int j = 0; j < 4; j++) w[i][j] = wr[j];
    }
    const float bc = bcomb[lane & 15];

    const float* srcb = (lane < 32) ? (x + k8) : (p + k8 - DIM_);

    float4 u0 = ((const float4*)(srcb + (size_t)m0 * DIM_))[0];
    float4 u1 = ((const float4*)(srcb + (size_t)m0 * DIM_))[1];

#pragma unroll
    for (int r = 0; r < 4; r++) {
        const int m = m0 + r;
        float4 n0, n1;
        if (r < 3) {
            n0 = ((const float4*)(srcb + (size_t)(m + 1) * DIM_))[0];
            n1 = ((const float4*)(srcb + (size_t)(m + 1) * DIM_))[1];
        }
        float uv[8] = { u0.x, u0.y, u0.z, u0.w, u1.x, u1.y, u1.z, u1.w };

        float s = 0.f, q2 = 0.f;
#pragma unroll
        for (int i = 0; i < 8; i++) { s += uv[i]; q2 += uv[i] * uv[i]; }
#pragma unroll
        for (int d = 1; d <= 16; d <<= 1) {
            s  += __shfl_xor(s, d);
            q2 += __shfl_xor(q2, d);
        }
        float mean_h = s * (1.f / 256.f);
        float var_h  = q2 * (1.f / 256.f) - mean_h * mean_h;
        float rstd_h = rsqrtf(var_h + 1e-5f);
        float sf  = s  + __shfl_xor(s, 32);
        float q2f = q2 + __shfl_xor(q2, 32);
        float mean_q = sf * (1.f / 512.f);
        float var_q  = q2f * (1.f / 512.f) - mean_q * mean_q;
        float rstd_q = rsqrtf(var_q + 1e-5f);

        v8s okv;
#pragma unroll
        for (int i = 0; i < 8; i++) okv[i] = f2b((uv[i] - mean_h) * rstd_h);
        short* akvdst = Akv + ((lane < 32) ? ((size_t)m * DIM_ + k8)
                                           : ((size_t)(BN_ + m) * DIM_ + k8 - DIM_));
        *(v8s*)akvdst = okv;

        float nv[8];
        v8s oq;
#pragma unroll
        for (int i = 0; i < 8; i++) { nv[i] = (uv[i] - mean_q) * rstd_q; oq[i] = f2b(nv[i]); }
        *(v8s*)(Aq + (size_t)m * INNER_ + k8) = oq;

        float acc[16];
#pragma unroll
        for (int h = 0; h < 16; h++) acc[h] = 0.f;
#pragma unroll
        for (int i = 0; i < 8; i++) {
            float nvi = nv[i];
            acc[0]  += nvi * w[i][0].x;  acc[1]  += nvi * w[i][0].y;
            acc[2]  += nvi * w[i][0].z;  acc[3]  += nvi * w[i][0].w;
            acc[4]  += nvi * w[i][1].x;  acc[5]  += nvi * w[i][1].y;
            acc[6]  += nvi * w[i][1].z;  acc[7]  += nvi * w[i][1].w;
            acc[8]  += nvi * w[i][2].x;  acc[9]  += nvi * w[i][2].y;
            acc[10] += nvi * w[i][2].z;  acc[11] += nvi * w[i][2].w;
            acc[12] += nvi * w[i][3].x;  acc[13] += nvi * w[i][3].y;
            acc[14] += nvi * w[i][3].z;  acc[15] += nvi * w[i][3].w;
        }
        float a8[8];
#pragma unroll
        for (int j = 0; j < 8; j++) {
            float lo = acc[2 * j] + __shfl_xor(acc[2 * j], 1);
            float hi = acc[2 * j + 1] + __shfl_xor(acc[2 * j + 1], 1);
            a8[j] = (lane & 1) ? hi : lo;
        }
        float a4[4];
#pragma unroll
        for (int j = 0; j < 4; j++) {
            float lo = a8[2 * j] + __shfl_xor(a8[2 * j], 2);
            float hi = a8[2 * j + 1] + __shfl_xor(a8[2 * j + 1], 2);
            a4[j] = (lane & 2) ? hi : lo;
        }
        float a2[2];
#pragma unroll
        for (int j = 0; j < 2; j++) {
            float lo = a4[2 * j] + __shfl_xor(a4[2 * j], 4);
            float hi = a4[2 * j + 1] + __shfl_xor(a4[2 * j + 1], 4);
            a2[j] = (lane & 4) ? hi : lo;
        }
        float l1 = a2[0] + __shfl_xor(a2[0], 8);
        float h1 = a2[1] + __shfl_xor(a2[1], 8);
        float a1 = (lane & 8) ? h1 : l1;
        a1 += __shfl_xor(a1, 16);
        a1 += __shfl_xor(a1, 32);

        if (lane < 16) {
            float off = a1 + bc;
            int b = m >> 12, n = m & (N_ - 1);
            int h = lane >> 1, pp = lane & 1;
            out_off[(size_t)((b * H_ + h) * P_ + pp) * N_ + n] = off;
            float f = fminf(fmaxf((float)n + off, 0.f), (float)(2 * N_ - 1));
            idx[((size_t)(b * H_ + h) * N_ + n) * P_ + pp] = (int)f;
        }
        u0 = n0; u1 = n1;
    }
}

// ---------------------------------------------------------------------------
// bf16 MFMA GEMM: C[M][N] = A[M][K] @ Bt[N][K]^T + bias.
// 128x128 tile, BK=64, 256 thr = 4 waves (2x2), 4x4 frags of 16x16x32 / wave.
//  - XCD swizzle: all gridDim.x column tiles of a row panel map to one XCD
//    (lin % 8 preserved across the panel) -> A fetched ~once from HBM.
//  - global_load_lds width=16 async staging (LDS dest = uniform + lane*16).
//  - XOR chunk swizzle (kc ^= row&7): fragment ds_read_b128 conflict-free.
//  - Epilogue: per-wave LDS transpose -> 16-contiguous-column stores per lane
//    (4-lane groups form 128 B segments; kills bf16 write amplification).
// ---------------------------------------------------------------------------
template <typename OT>
__global__ __launch_bounds__(256) void gemm_mfma(
    const short* __restrict__ A, const short* __restrict__ Bt,
    const float* __restrict__ bias, OT* __restrict__ C, int M, int N, int K) {
    __shared__ short smem[2 * 128 * 64];   // As | Bs (32 KB); reused by epilogue
    short* As = smem;
    short* Bs = smem + 128 * 64;
    const int tid  = threadIdx.x;
    const int lane = tid & 63, w = tid >> 6;
    const int wr = w >> 1, wc = w & 1;
    const int lm = lane & 15, g = lane >> 4;

    // XCD swizzle (gridDim.y must be a multiple of 8)
    const int nx  = gridDim.x;
    const int lin = blockIdx.y * nx + blockIdx.x;
    const int x8 = lin & 7, t = lin >> 3;
    const int bx = t % nx, by = (t / nx) * 8 + x8;
    const int row0 = by * 128, col0 = bx * 128;

    v4f acc[4][4];
#pragma unroll
    for (int i = 0; i < 4; i++)
#pragma unroll
        for (int j = 0; j < 4; j++) acc[i][j] = (v4f){0.f, 0.f, 0.f, 0.f};

    for (int k0 = 0; k0 < K; k0 += 64) {
        __syncthreads();   // previous iteration's fragment reads complete
#pragma unroll
        for (int r = 0; r < 4; r++) {
            int s   = tid + 256 * r;        // LDS chunk slot (16 B each)
            int row = s >> 3, kcs = s & 7;
            int kg  = kcs ^ (row & 7);      // global k-chunk stored at this slot
            async16(A  + (size_t)(row0 + row) * K + k0 + kg * 8, (char*)As + s * 16);
            async16(Bt + (size_t)(col0 + row) * K + k0 + kg * 8, (char*)Bs + s * 16);
        }
        __syncthreads();   // drains vmcnt -> LDS valid
#pragma unroll
        for (int ks = 0; ks < 2; ks++) {
            v8s af[4], bf[4];
#pragma unroll
            for (int i = 0; i < 4; i++) {
                int m   = wr * 64 + i * 16 + lm;
                int sch = m * 8 + ((ks * 4 + g) ^ (m & 7));
                af[i] = *(const v8s*)(As + sch * 8);
            }
#pragma unroll
            for (int j = 0; j < 4; j++) {
                int n   = wc * 64 + j * 16 + lm;
                int sch = n * 8 + ((ks * 4 + g) ^ (n & 7));
                bf[j] = *(const v8s*)(Bs + sch * 8);
            }
#pragma unroll
            for (int i = 0; i < 4; i++)
#pragma unroll
                for (int j = 0; j < 4; j++)
                    acc[i][j] = __builtin_amdgcn_mfma_f32_16x16x32_bf16(af[i], bf[j], acc[i][j], 0, 0, 0);
        }
    }

    // bias add in-register
#pragma unroll
    for (int j = 0; j < 4; j++) {
        int gc = col0 + wc * 64 + j * 16 + lm;
        float bj = bias ? bias[gc] : 0.f;
#pragma unroll
        for (int i = 0; i < 4; i++)
#pragma unroll
            for (int r = 0; r < 4; r++) acc[i][j][r] += bj;
    }

    // epilogue: per-wave 16x64 fp32 transpose through LDS (stride 68, 2-way max)
    __syncthreads();
    float* ep = (float*)smem + w * (16 * 68);
#pragma unroll
    for (int i = 0; i < 4; i++) {
#pragma unroll
        for (int j = 0; j < 4; j++)
#pragma unroll
            for (int r = 0; r < 4; r++)
                ep[(g * 4 + r) * 68 + j * 16 + lm] = acc[i][j][r];
        __syncthreads();
        int rr = lane >> 2, cb = (lane & 3) * 16;
        float4 f0 = *(float4*)(ep + rr * 68 + cb + 0);
        float4 f1 = *(float4*)(ep + rr * 68 + cb + 4);
        float4 f2 = *(float4*)(ep + rr * 68 + cb + 8);
        float4 f3 = *(float4*)(ep + rr * 68 + cb + 12);
        __syncthreads();
        int grow = row0 + wr * 64 + i * 16 + rr;
        int gcol = col0 + wc * 64 + cb;
        storeRow(&C[(size_t)grow * N + gcol], f0, f1, f2, f3);
    }
}

// ---------------------------------------------------------------------------
// Attention: wave per 2 samples (2-way ILP on the shuffle chains).
// kvproj layout [row][1024]: k cols 0-511, v 512+.
// ---------------------------------------------------------------------------
__global__ __launch_bounds__(256) void attn_kernel(
    const short* __restrict__ qb, const short* __restrict__ kvproj,
    const int* __restrict__ idx, short* __restrict__ attnout) {
    int lane = threadIdx.x & 63;
    int wv   = threadIdx.x >> 6;
    int n0 = blockIdx.x * 8 + wv * 2;
    int h = blockIdx.y, b = blockIdx.z;
    int mA = b * N_ + n0, mB = mA + 1;

    float qA = b2f(qb[(size_t)mA * INNER_ + h * DH_ + lane]) * 0.125f;
    float qB = b2f(qb[(size_t)mB * INNER_ + h * DH_ + lane]) * 0.125f;

    const int* ipA = idx + ((size_t)(b * H_ + h) * N_ + n0) * P_;
    int jA0 = ipA[0], jA1 = ipA[1], jB0 = ipA[2], jB1 = ipA[3];
    int rA0 = b * N_ + jA0 + ((jA0 >= N_) ? (BN_ - N_) : 0);
    int rA1 = b * N_ + jA1 + ((jA1 >= N_) ? (BN_ - N_) : 0);
    int rB0 = b * N_ + jB0 + ((jB0 >= N_) ? (BN_ - N_) : 0);
    int rB1 = b * N_ + jB1 + ((jB1 >= N_) ? (BN_ - N_) : 0);
    size_t oA0 = (size_t)rA0 * 1024 + h * DH_ + lane;
    size_t oA1 = (size_t)rA1 * 1024 + h * DH_ + lane;
    size_t oB0 = (size_t)rB0 * 1024 + h * DH_ + lane;
    size_t oB1 = (size_t)rB1 * 1024 + h * DH_ + lane;

    float kA0 = b2f(kvproj[oA0]),       kA1 = b2f(kvproj[oA1]);
    float kB0 = b2f(kvproj[oB0]),       kB1 = b2f(kvproj[oB1]);
    float vA0 = b2f(kvproj[oA0 + 512]), vA1 = b2f(kvproj[oA1 + 512]);
    float vB0 = b2f(kvproj[oB0 + 512]), vB1 = b2f(kvproj[oB1 + 512]);

    float sA0 = qA * kA0, sA1 = qA * kA1;
    float sB0 = qB * kB0, sB1 = qB * kB1;
    for (int d = 1; d < 64; d <<= 1) {
        sA0 += __shfl_xor(sA0, d);
        sA1 += __shfl_xor(sA1, d);
        sB0 += __shfl_xor(sB0, d);
        sB1 += __shfl_xor(sB1, d);
    }
    float mxA = fmaxf(sA0, sA1), mxB = fmaxf(sB0, sB1);
    float eA0 = __expf(sA0 - mxA), eA1 = __expf(sA1 - mxA);
    float eB0 = __expf(sB0 - mxB), eB1 = __expf(sB1 - mxB);
    float invA = 1.f / (eA0 + eA1), invB = 1.f / (eB0 + eB1);
    attnout[(size_t)mA * INNER_ + h * DH_ + lane] = f2b((eA0 * vA0 + eA1 * vA1) * invA);
    attnout[(size_t)mB * INNER_ + h * DH_ + lane] = f2b((eB0 * vB0 + eB1 * vB1) * invB);
}

// ---------------------------------------------------------------------------
extern "C" void kernel_launch(void* const* d_in, const int* in_sizes, int n_in,
                              void* d_out, int out_size, void* d_ws, size_t ws_size,
                              hipStream_t stream) {
    (void)in_sizes; (void)n_in; (void)out_size; (void)ws_size;

    const float* x      = (const float*)d_in[0];
    const float* prevx  = (const float*)d_in[1];
    const float* ln_q_g = (const float*)d_in[2];
    const float* ln_q_b = (const float*)d_in[3];
    const float* ln_k_g = (const float*)d_in[4];
    const float* ln_k_b = (const float*)d_in[5];
    const float* ln_v_g = (const float*)d_in[6];
    const float* ln_v_b = (const float*)d_in[7];
    const float* Wq     = (const float*)d_in[8];
    const float* Wk     = (const float*)d_in[9];
    const float* bk     = (const float*)d_in[10];
    const float* Wv     = (const float*)d_in[11];
    const float* bv     = (const float*)d_in[12];
    const float* Woff   = (const float*)d_in[13];
    const float* boff   = (const float*)d_in[14];
    const float* Wout   = (const float*)d_in[15];
    const float* bout   = (const float*)d_in[16];

    char* cur = (char*)d_ws;
    auto alloc = [&](size_t bytes) { char* p = cur; cur += (bytes + 255) & ~(size_t)255; return p; };
    short* Aq      = (short*)alloc((size_t)BN_ * INNER_ * 2);     // 16 MB
    short* Akv     = (short*)alloc((size_t)KVR_ * DIM_ * 2);      // 16 MB
    short* qb      = (short*)alloc((size_t)BN_ * INNER_ * 2);     // 16 MB
    short* kvproj  = (short*)alloc((size_t)KVR_ * 1024 * 2);      // 64 MB
    short* attnout = (short*)alloc((size_t)BN_ * INNER_ * 2);     // 16 MB
    short* Wq2t    = (short*)alloc(512 * 512 * 2);
    short* Wkvt    = (short*)alloc(1024 * 256 * 2);
    short* Woutb   = (short*)alloc(256 * 512 * 2);
    float* bq2     = (float*)alloc(512 * 4);
    float* bkv     = (float*)alloc(1024 * 4);
    float* Wcomb   = (float*)alloc(512 * 16 * 4);
    float* bcomb   = (float*)alloc(16 * 4);
    int*   idxb    = (int*)alloc((size_t)BN_ * 16 * 4);
    // total ~130 MB

    float* out_main = (float*)d_out;                      // (B,N,DIM)
    float* out_off  = out_main + (size_t)BN_ * DIM_;      // (B,H,P,N)

    // 1) weight prep (transposed bf16, LN-folded) + composed offset weights
    prep_t<<<512, 256, 0, stream>>>(Wq, ln_q_g, ln_q_b, nullptr, Wq2t, bq2, 512, 512);
    prep_t<<<512, 256, 0, stream>>>(Wk, ln_k_g, ln_k_b, bk, Wkvt, bkv, 256, 512);
    prep_t<<<512, 256, 0, stream>>>(Wv, ln_v_g, ln_v_b, bv, Wkvt + 512 * 256, bkv + 512, 256, 512);
    cast_bf16<<<512, 256, 0, stream>>>(Wout, Woutb, 256 * 512);
    wcomb_kernel<<<512, 256, 0, stream>>>(Wq, ln_q_g, Woff, Wcomb);
    bcomb_kernel<<<1, 256, 0, stream>>>(bq2, Woff, boff, bcomb);

    // 2) single-pass fused LN + activations + offsets + indices (4 rows/wave)
    norm_fused_kernel<<<BN_ / 16, 256, 0, stream>>>(x, prevx, Wcomb, bcomb,
                                                    Aq, Akv, out_off, idxb);

    // 3) MFMA GEMMs
    gemm_mfma<__hip_bfloat16><<<dim3(INNER_ / 128, BN_ / 128), 256, 0, stream>>>(
        Aq, Wq2t, bq2, (__hip_bfloat16*)qb, BN_, INNER_, 512);
    gemm_mfma<__hip_bfloat16><<<dim3(1024 / 128, KVR_ / 128), 256, 0, stream>>>(
        Akv, Wkvt, bkv, (__hip_bfloat16*)kvproj, KVR_, 1024, 256);

    // 4) gather + softmax(P=2) + weighted sum (2 samples per wave)
    dim3 ga(N_ / 8, H_, B_);
    attn_kernel<<<ga, 256, 0, stream>>>(qb, kvproj, idxb, attnout);

    // 5) output projection
    gemm_mfma<float><<<dim3(DIM_ / 128, BN_ / 128), 256, 0, stream>>>(
        attnout, Woutb, bout, out_main, BN_, DIM_, 512);
}

// Round 9
// 224.004 us; speedup vs baseline: 3.1661x; 1.1001x over previous
//
#include <hip/hip_runtime.h>
#include <hip/hip_bf16.h>
#include <math.h>

#define B_    4
#define N_    4096
#define DIM_  256
#define H_    8
#define DH_   64
#define P_    2
#define INNER_ 512
#define BN_   (B_ * N_)      // 16384 rows for q/out
#define KVR_  (2 * BN_)      // 32768 rows for k/v

typedef short v8s  __attribute__((ext_vector_type(8)));
typedef short v4s  __attribute__((ext_vector_type(4)));
typedef float v4f  __attribute__((ext_vector_type(4)));

__device__ __forceinline__ short f2b(float x) {
    __hip_bfloat16 h = __float2bfloat16(x);
    return *reinterpret_cast<short*>(&h);
}
__device__ __forceinline__ float b2f(short s) {
    __hip_bfloat16 h = *reinterpret_cast<__hip_bfloat16*>(&s);
    return __bfloat162float(h);
}

__device__ __forceinline__ void async16(const void* g, void* l) {
    __builtin_amdgcn_global_load_lds(
        (const __attribute__((address_space(1))) void*)g,
        (__attribute__((address_space(3))) void*)l, 16, 0, 0);
}

// 16 consecutive elements of one row -> wide stores
__device__ __forceinline__ void storeRow(float* p, float4 f0, float4 f1, float4 f2, float4 f3) {
    ((float4*)p)[0] = f0; ((float4*)p)[1] = f1; ((float4*)p)[2] = f2; ((float4*)p)[3] = f3;
}
__device__ __forceinline__ void storeRow(__hip_bfloat16* p, float4 f0, float4 f1, float4 f2, float4 f3) {
    v8s o0, o1;
    o0[0]=f2b(f0.x); o0[1]=f2b(f0.y); o0[2]=f2b(f0.z); o0[3]=f2b(f0.w);
    o0[4]=f2b(f1.x); o0[5]=f2b(f1.y); o0[6]=f2b(f1.z); o0[7]=f2b(f1.w);
    o1[0]=f2b(f2.x); o1[1]=f2b(f2.y); o1[2]=f2b(f2.z); o1[3]=f2b(f2.w);
    o1[4]=f2b(f3.x); o1[5]=f2b(f3.y); o1[6]=f2b(f3.z); o1[7]=f2b(f3.w);
    ((v8s*)p)[0] = o0; ((v8s*)p)[1] = o1;
}

// ---------------------------------------------------------------------------
// MERGED weight prep, one dispatch:
//  blocks [0,512)     : Wq  fold+transpose (+0.125 attn-scale fold) -> Wq2t,bq2
//  blocks [512,1024)  : Wk  fold+transpose -> Wkvt[0:512], bkv[0:512]
//  blocks [1024,1536) : Wv  fold+transpose -> Wkvt[512:1024], bkv[512:1024]
//  blocks [1536,2048) : Wcomb row k = gq[k] * (Wq@Woff^T)[k]; braw = betaq[k]*raw
//  blocks [2048,2176) : Wout fp32->bf16 cast (128 blocks x 1024 elems)
// ---------------------------------------------------------------------------
__global__ __launch_bounds__(256) void prep_all(
    const float* __restrict__ Wq, const float* __restrict__ gq, const float* __restrict__ betaq,
    const float* __restrict__ Wk, const float* __restrict__ gk, const float* __restrict__ betak,
    const float* __restrict__ bk,
    const float* __restrict__ Wv, const float* __restrict__ gv, const float* __restrict__ betav,
    const float* __restrict__ bv,
    const float* __restrict__ Woff, const float* __restrict__ Wout,
    short* __restrict__ Wq2t, float* __restrict__ bq2,
    short* __restrict__ Wkvt, float* __restrict__ bkv,
    float* __restrict__ Wcomb, float* __restrict__ braw, short* __restrict__ Woutb) {
    __shared__ float sm[272];
    const int bid = blockIdx.x, t = threadIdx.x;

    if (bid < 1536) {
        const float *W, *g, *beta, *bias_in;
        short* Wt; float* b2; int K, n; float scale;
        if (bid < 512)       { W=Wq; g=gq; beta=betaq; bias_in=nullptr; Wt=Wq2t; b2=bq2; K=512; n=bid;        scale=0.125f; }
        else if (bid < 1024) { W=Wk; g=gk; beta=betak; bias_in=bk; Wt=Wkvt;           b2=bkv;       K=256; n=bid-512;  scale=1.f; }
        else                 { W=Wv; g=gv; beta=betav; bias_in=bv; Wt=Wkvt+512*256;   b2=bkv+512;   K=256; n=bid-1024; scale=1.f; }
        float partial = 0.f;
        for (int k = t; k < K; k += 256) {
            float w = W[k * 512 + n];
            Wt[(size_t)n * K + k] = f2b(scale * g[k] * w);
            partial += beta[k] * w;
        }
        sm[t] = partial;
        __syncthreads();
        for (int s = 128; s > 0; s >>= 1) {
            if (t < s) sm[t] += sm[t + s];
            __syncthreads();
        }
        if (t == 0) b2[n] = scale * ((bias_in ? bias_in[n] : 0.f) + sm[0]);
    } else if (bid < 2048) {
        const int k = bid - 1536;
        const int hp = t & 15, jg = t >> 4;
        float p = 0.f;
        for (int j = jg; j < INNER_; j += 16)
            p += Wq[k * INNER_ + j] * Woff[hp * INNER_ + j];
        sm[jg * 17 + hp] = p;
        __syncthreads();
        if (t < 16) {
            float s = 0.f;
            for (int i = 0; i < 16; i++) s += sm[i * 17 + t];
            Wcomb[k * 16 + t] = gq[k] * s;
            braw[k * 16 + t]  = betaq[k] * s;
        }
    } else {
        const int i0 = (bid - 2048) * 1024 + t * 4;
        float4 f = *(const float4*)(Wout + i0);
        v4s o;
        o[0] = f2b(f.x); o[1] = f2b(f.y); o[2] = f2b(f.z); o[3] = f2b(f.w);
        *(v4s*)(Woutb + i0) = o;
    }
}

// bcomb[hp] = sum_k braw[k][hp] + boff[hp]  (deterministic 1-block reduce)
__global__ void bcomb_sum(const float* __restrict__ braw, const float* __restrict__ boff,
                          float* __restrict__ bcomb) {
    __shared__ float sm[272];
    int t = threadIdx.x;
    int hp = t & 15, kg = t >> 4;
    float p = 0.f;
    for (int k = kg; k < 512; k += 16) p += braw[k * 16 + hp];
    sm[kg * 17 + hp] = p;
    __syncthreads();
    if (t < 16) {
        float s = 0.f;
        for (int i = 0; i < 16; i++) s += sm[i * 17 + t];
        bcomb[t] = s + boff[t];
    }
}

// ---------------------------------------------------------------------------
// FUSED single-pass LN + activations + offsets. One wave per 4 rows.
// Wcomb slice register-resident; per-row pure FMA + butterfly reductions.
// ---------------------------------------------------------------------------
__global__ __launch_bounds__(256) void norm_fused_kernel(
    const float* __restrict__ x, const float* __restrict__ p,
    const float* __restrict__ Wcomb, const float* __restrict__ bcomb,
    short* __restrict__ Aq, short* __restrict__ Akv,
    float* __restrict__ out_off, int* __restrict__ idx) {
    const int lane = threadIdx.x & 63;
    const int wv   = threadIdx.x >> 6;
    const int m0   = (blockIdx.x * 4 + wv) * 4;   // first of 4 rows
    const int k8   = lane * 8;

    float4 w[8][4];
#pragma unroll
    for (int i = 0; i < 8; i++) {
        const float4* wr = (const float4*)(Wcomb + (size_t)(k8 + i) * 16);
#pragma unroll
        for (int j = 0; j < 4; j++) w[i][j] = wr[j];
    }
    const float bc = bcomb[lane & 15];

    const float* srcb = (lane < 32) ? (x + k8) : (p + k8 - DIM_);

    float4 u0 = ((const float4*)(srcb + (size_t)m0 * DIM_))[0];
    float4 u1 = ((const float4*)(srcb + (size_t)m0 * DIM_))[1];

#pragma unroll
    for (int r = 0; r < 4; r++) {
        const int m = m0 + r;
        float4 n0, n1;
        if (r < 3) {
            n0 = ((const float4*)(srcb + (size_t)(m + 1) * DIM_))[0];
            n1 = ((const float4*)(srcb + (size_t)(m + 1) * DIM_))[1];
        }
        float uv[8] = { u0.x, u0.y, u0.z, u0.w, u1.x, u1.y, u1.z, u1.w };

        float s = 0.f, q2 = 0.f;
#pragma unroll
        for (int i = 0; i < 8; i++) { s += uv[i]; q2 += uv[i] * uv[i]; }
#pragma unroll
        for (int d = 1; d <= 16; d <<= 1) {
            s  += __shfl_xor(s, d);
            q2 += __shfl_xor(q2, d);
        }
        float mean_h = s * (1.f / 256.f);
        float var_h  = q2 * (1.f / 256.f) - mean_h * mean_h;
        float rstd_h = rsqrtf(var_h + 1e-5f);
        float sf  = s  + __shfl_xor(s, 32);
        float q2f = q2 + __shfl_xor(q2, 32);
        float mean_q = sf * (1.f / 512.f);
        float var_q  = q2f * (1.f / 512.f) - mean_q * mean_q;
        float rstd_q = rsqrtf(var_q + 1e-5f);

        v8s okv;
#pragma unroll
        for (int i = 0; i < 8; i++) okv[i] = f2b((uv[i] - mean_h) * rstd_h);
        short* akvdst = Akv + ((lane < 32) ? ((size_t)m * DIM_ + k8)
                                           : ((size_t)(BN_ + m) * DIM_ + k8 - DIM_));
        *(v8s*)akvdst = okv;

        float nv[8];
        v8s oq;
#pragma unroll
        for (int i = 0; i < 8; i++) { nv[i] = (uv[i] - mean_q) * rstd_q; oq[i] = f2b(nv[i]); }
        *(v8s*)(Aq + (size_t)m * INNER_ + k8) = oq;

        float acc[16];
#pragma unroll
        for (int h = 0; h < 16; h++) acc[h] = 0.f;
#pragma unroll
        for (int i = 0; i < 8; i++) {
            float nvi = nv[i];
            acc[0]  += nvi * w[i][0].x;  acc[1]  += nvi * w[i][0].y;
            acc[2]  += nvi * w[i][0].z;  acc[3]  += nvi * w[i][0].w;
            acc[4]  += nvi * w[i][1].x;  acc[5]  += nvi * w[i][1].y;
            acc[6]  += nvi * w[i][1].z;  acc[7]  += nvi * w[i][1].w;
            acc[8]  += nvi * w[i][2].x;  acc[9]  += nvi * w[i][2].y;
            acc[10] += nvi * w[i][2].z;  acc[11] += nvi * w[i][2].w;
            acc[12] += nvi * w[i][3].x;  acc[13] += nvi * w[i][3].y;
            acc[14] += nvi * w[i][3].z;  acc[15] += nvi * w[i][3].w;
        }
        float a8[8];
#pragma unroll
        for (int j = 0; j < 8; j++) {
            float lo = acc[2 * j] + __shfl_xor(acc[2 * j], 1);
            float hi = acc[2 * j + 1] + __shfl_xor(acc[2 * j + 1], 1);
            a8[j] = (lane & 1) ? hi : lo;
        }
        float a4[4];
#pragma unroll
        for (int j = 0; j < 4; j++) {
            float lo = a8[2 * j] + __shfl_xor(a8[2 * j], 2);
            float hi = a8[2 * j + 1] + __shfl_xor(a8[2 * j + 1], 2);
            a4[j] = (lane & 2) ? hi : lo;
        }
        float a2[2];
#pragma unroll
        for (int j = 0; j < 2; j++) {
            float lo = a4[2 * j] + __shfl_xor(a4[2 * j], 4);
            float hi = a4[2 * j + 1] + __shfl_xor(a4[2 * j + 1], 4);
            a2[j] = (lane & 4) ? hi : lo;
        }
        float l1 = a2[0] + __shfl_xor(a2[0], 8);
        float h1 = a2[1] + __shfl_xor(a2[1], 8);
        float a1 = (lane & 8) ? h1 : l1;
        a1 += __shfl_xor(a1, 16);
        a1 += __shfl_xor(a1, 32);

        if (lane < 16) {
            float off = a1 + bc;
            int b = m >> 12, n = m & (N_ - 1);
            int h = lane >> 1, pp = lane & 1;
            out_off[(size_t)((b * H_ + h) * P_ + pp) * N_ + n] = off;
            float f = fminf(fmaxf((float)n + off, 0.f), (float)(2 * N_ - 1));
            idx[((size_t)(b * H_ + h) * N_ + n) * P_ + pp] = (int)f;
        }
        u0 = n0; u1 = n1;
    }
}

// ---------------------------------------------------------------------------
// bf16 MFMA GEMM body: C[.][N] = A[.][K] @ Bt[N][K]^T + bias.
// 128x128 tile, BK=64, 4 waves (2x2), 4x4 frags of 16x16x32 / wave.
// XCD swizzle on lin (panel pinned to one XCD); async global_load_lds w=16;
// XOR chunk swizzle; LDS-transposed wide-store epilogue.
// ---------------------------------------------------------------------------
template <typename OT>
__device__ __forceinline__ void gemm_body(
    short* smem, const short* __restrict__ A, const short* __restrict__ Bt,
    const float* __restrict__ bias, OT* __restrict__ C, int N, int K, int nx, int lin) {
    short* As = smem;
    short* Bs = smem + 128 * 64;
    const int tid  = threadIdx.x;
    const int lane = tid & 63, w = tid >> 6;
    const int wr = w >> 1, wc = w & 1;
    const int lm = lane & 15, g = lane >> 4;

    const int x8 = lin & 7, t = lin >> 3;
    const int bx = t % nx, by = (t / nx) * 8 + x8;
    const int row0 = by * 128, col0 = bx * 128;

    v4f acc[4][4];
#pragma unroll
    for (int i = 0; i < 4; i++)
#pragma unroll
        for (int j = 0; j < 4; j++) acc[i][j] = (v4f){0.f, 0.f, 0.f, 0.f};

    for (int k0 = 0; k0 < K; k0 += 64) {
        __syncthreads();
#pragma unroll
        for (int r = 0; r < 4; r++) {
            int s   = tid + 256 * r;
            int row = s >> 3, kcs = s & 7;
            int kg  = kcs ^ (row & 7);
            async16(A  + (size_t)(row0 + row) * K + k0 + kg * 8, (char*)As + s * 16);
            async16(Bt + (size_t)(col0 + row) * K + k0 + kg * 8, (char*)Bs + s * 16);
        }
        __syncthreads();
#pragma unroll
        for (int ks = 0; ks < 2; ks++) {
            v8s af[4], bf[4];
#pragma unroll
            for (int i = 0; i < 4; i++) {
                int m   = wr * 64 + i * 16 + lm;
                int sch = m * 8 + ((ks * 4 + g) ^ (m & 7));
                af[i] = *(const v8s*)(As + sch * 8);
            }
#pragma unroll
            for (int j = 0; j < 4; j++) {
                int n   = wc * 64 + j * 16 + lm;
                int sch = n * 8 + ((ks * 4 + g) ^ (n & 7));
                bf[j] = *(const v8s*)(Bs + sch * 8);
            }
#pragma unroll
            for (int i = 0; i < 4; i++)
#pragma unroll
                for (int j = 0; j < 4; j++)
                    acc[i][j] = __builtin_amdgcn_mfma_f32_16x16x32_bf16(af[i], bf[j], acc[i][j], 0, 0, 0);
        }
    }

#pragma unroll
    for (int j = 0; j < 4; j++) {
        int gc = col0 + wc * 64 + j * 16 + lm;
        float bj = bias ? bias[gc] : 0.f;
#pragma unroll
        for (int i = 0; i < 4; i++)
#pragma unroll
            for (int r = 0; r < 4; r++) acc[i][j][r] += bj;
    }

    __syncthreads();
    float* ep = (float*)smem + w * (16 * 68);
#pragma unroll
    for (int i = 0; i < 4; i++) {
#pragma unroll
        for (int j = 0; j < 4; j++)
#pragma unroll
            for (int r = 0; r < 4; r++)
                ep[(g * 4 + r) * 68 + j * 16 + lm] = acc[i][j][r];
        __syncthreads();
        int rr = lane >> 2, cb = (lane & 3) * 16;
        float4 f0 = *(float4*)(ep + rr * 68 + cb + 0);
        float4 f1 = *(float4*)(ep + rr * 68 + cb + 4);
        float4 f2 = *(float4*)(ep + rr * 68 + cb + 8);
        float4 f3 = *(float4*)(ep + rr * 68 + cb + 12);
        __syncthreads();
        int grow = row0 + wr * 64 + i * 16 + rr;
        int gcol = col0 + wc * 64 + cb;
        storeRow(&C[(size_t)grow * N + gcol], f0, f1, f2, f3);
    }
}

// merged q + kv projection GEMMs (independent; block-range dispatch)
__global__ __launch_bounds__(256) void gemm_qkv(
    const short* __restrict__ Aq, const short* __restrict__ Wq2t,
    const float* __restrict__ bq2, __hip_bfloat16* __restrict__ qb,
    const short* __restrict__ Akv, const short* __restrict__ Wkvt,
    const float* __restrict__ bkv, __hip_bfloat16* __restrict__ kvproj) {
    __shared__ short smem[2 * 128 * 64];
    const int bid = blockIdx.x;
    if (bid < 512)
        gemm_body<__hip_bfloat16>(smem, Aq, Wq2t, bq2, qb, 512, 512, 4, bid);
    else
        gemm_body<__hip_bfloat16>(smem, Akv, Wkvt, bkv, kvproj, 1024, 256, 8, bid - 512);
}

// output projection GEMM
__global__ __launch_bounds__(256) void gemm_out(
    const short* __restrict__ A, const short* __restrict__ Bt,
    const float* __restrict__ bias, float* __restrict__ C) {
    __shared__ short smem[2 * 128 * 64];
    const int lin = blockIdx.y * gridDim.x + blockIdx.x;
    gemm_body<float>(smem, A, Bt, bias, C, 256, 512, 2, lin);
}

// ---------------------------------------------------------------------------
// Attention: 16-lane groups, 4 samples/wave. Lane owns 4-elem DH slice.
// kvproj layout [row][1024]: k cols 0-511, v 512+. q pre-scaled by 0.125.
// ---------------------------------------------------------------------------
__global__ __launch_bounds__(256) void attn_kernel(
    const short* __restrict__ qb, const short* __restrict__ kvproj,
    const int* __restrict__ idx, short* __restrict__ attnout) {
    const int lane = threadIdx.x & 63;
    const int wv   = threadIdx.x >> 6;
    const int s    = lane >> 4, c = lane & 15;
    const int n = blockIdx.x * 16 + wv * 4 + s;
    const int h = blockIdx.y, b = blockIdx.z;
    const int m = b * N_ + n;

    v4s qv = *(const v4s*)(qb + (size_t)m * INNER_ + h * DH_ + c * 4);

    const int* ip = idx + ((size_t)(b * H_ + h) * N_ + n) * P_;
    int j0 = ip[0], j1 = ip[1];
    int r0 = b * N_ + j0 + ((j0 >= N_) ? (BN_ - N_) : 0);
    int r1 = b * N_ + j1 + ((j1 >= N_) ? (BN_ - N_) : 0);
    const short* k0p = kvproj + (size_t)r0 * 1024 + h * DH_ + c * 4;
    const short* k1p = kvproj + (size_t)r1 * 1024 + h * DH_ + c * 4;
    v4s k0 = *(const v4s*)k0p, v0 = *(const v4s*)(k0p + 512);
    v4s k1 = *(const v4s*)k1p, v1 = *(const v4s*)(k1p + 512);

    float q0 = b2f(qv[0]), q1 = b2f(qv[1]), q2 = b2f(qv[2]), q3 = b2f(qv[3]);
    float s0 = q0 * b2f(k0[0]) + q1 * b2f(k0[1]) + q2 * b2f(k0[2]) + q3 * b2f(k0[3]);
    float s1 = q0 * b2f(k1[0]) + q1 * b2f(k1[1]) + q2 * b2f(k1[2]) + q3 * b2f(k1[3]);
#pragma unroll
    for (int d = 1; d <= 8; d <<= 1) {
        s0 += __shfl_xor(s0, d);
        s1 += __shfl_xor(s1, d);
    }
    float mx = fmaxf(s0, s1);
    float e0 = __expf(s0 - mx), e1 = __expf(s1 - mx);
    float inv = 1.f / (e0 + e1);
    v4s o;
#pragma unroll
    for (int i = 0; i < 4; i++)
        o[i] = f2b((e0 * b2f(v0[i]) + e1 * b2f(v1[i])) * inv);
    *(v4s*)(attnout + (size_t)m * INNER_ + h * DH_ + c * 4) = o;
}

// ---------------------------------------------------------------------------
extern "C" void kernel_launch(void* const* d_in, const int* in_sizes, int n_in,
                              void* d_out, int out_size, void* d_ws, size_t ws_size,
                              hipStream_t stream) {
    (void)in_sizes; (void)n_in; (void)out_size; (void)ws_size;

    const float* x      = (const float*)d_in[0];
    const float* prevx  = (const float*)d_in[1];
    const float* ln_q_g = (const float*)d_in[2];
    const float* ln_q_b = (const float*)d_in[3];
    const float* ln_k_g = (const float*)d_in[4];
    const float* ln_k_b = (const float*)d_in[5];
    const float* ln_v_g = (const float*)d_in[6];
    const float* ln_v_b = (const float*)d_in[7];
    const float* Wq     = (const float*)d_in[8];
    const float* Wk     = (const float*)d_in[9];
    const float* bk     = (const float*)d_in[10];
    const float* Wv     = (const float*)d_in[11];
    const float* bv     = (const float*)d_in[12];
    const float* Woff   = (const float*)d_in[13];
    const float* boff   = (const float*)d_in[14];
    const float* Wout   = (const float*)d_in[15];
    const float* bout   = (const float*)d_in[16];

    char* cur = (char*)d_ws;
    auto alloc = [&](size_t bytes) { char* p = cur; cur += (bytes + 255) & ~(size_t)255; return p; };
    short* Aq      = (short*)alloc((size_t)BN_ * INNER_ * 2);     // 16 MB
    short* Akv     = (short*)alloc((size_t)KVR_ * DIM_ * 2);      // 16 MB
    short* qb      = (short*)alloc((size_t)BN_ * INNER_ * 2);     // 16 MB
    short* kvproj  = (short*)alloc((size_t)KVR_ * 1024 * 2);      // 64 MB
    short* attnout = (short*)alloc((size_t)BN_ * INNER_ * 2);     // 16 MB
    short* Wq2t    = (short*)alloc(512 * 512 * 2);
    short* Wkvt    = (short*)alloc(1024 * 256 * 2);
    short* Woutb   = (short*)alloc(256 * 512 * 2);
    float* bq2     = (float*)alloc(512 * 4);
    float* bkv     = (float*)alloc(1024 * 4);
    float* Wcomb   = (float*)alloc(512 * 16 * 4);
    float* braw    = (float*)alloc(512 * 16 * 4);
    float* bcomb   = (float*)alloc(16 * 4);
    int*   idxb    = (int*)alloc((size_t)BN_ * 16 * 4);
    // total ~130 MB

    float* out_main = (float*)d_out;                      // (B,N,DIM)
    float* out_off  = out_main + (size_t)BN_ * DIM_;      // (B,H,P,N)

    // 1) merged weight prep + composed offset weights
    prep_all<<<2176, 256, 0, stream>>>(Wq, ln_q_g, ln_q_b,
                                       Wk, ln_k_g, ln_k_b, bk,
                                       Wv, ln_v_g, ln_v_b, bv,
                                       Woff, Wout,
                                       Wq2t, bq2, Wkvt, bkv, Wcomb, braw, Woutb);
    bcomb_sum<<<1, 256, 0, stream>>>(braw, boff, bcomb);

    // 2) single-pass fused LN + activations + offsets + indices (4 rows/wave)
    norm_fused_kernel<<<BN_ / 16, 256, 0, stream>>>(x, prevx, Wcomb, bcomb,
                                                    Aq, Akv, out_off, idxb);

    // 3) q + kv projections, one dispatch
    gemm_qkv<<<2560, 256, 0, stream>>>(Aq, Wq2t, bq2, (__hip_bfloat16*)qb,
                                       Akv, Wkvt, bkv, (__hip_bfloat16*)kvproj);

    // 4) gather + softmax(P=2) + weighted sum (16-lane groups, 4 samples/wave)
    dim3 ga(N_ / 16, H_, B_);
    attn_kernel<<<ga, 256, 0, stream>>>(qb, kvproj, idxb, attnout);

    // 5) output projection
    gemm_out<<<dim3(2, 128), 256, 0, stream>>>(attnout, Woutb, bout, out_main);
}

// Round 10
// 220.620 us; speedup vs baseline: 3.2146x; 1.0153x over previous
//
#include <hip/hip_runtime.h>
#include <hip/hip_bf16.h>
#include <math.h>

#define B_    4
#define N_    4096
#define DIM_  256
#define H_    8
#define DH_   64
#define P_    2
#define INNER_ 512
#define BN_   (B_ * N_)      // 16384 rows for q/out
#define KVR_  (2 * BN_)      // 32768 rows for k/v

typedef short v8s  __attribute__((ext_vector_type(8)));
typedef short v4s  __attribute__((ext_vector_type(4)));
typedef float v4f  __attribute__((ext_vector_type(4)));

__device__ __forceinline__ short f2b(float x) {
    __hip_bfloat16 h = __float2bfloat16(x);
    return *reinterpret_cast<short*>(&h);
}
__device__ __forceinline__ float b2f(short s) {
    __hip_bfloat16 h = *reinterpret_cast<__hip_bfloat16*>(&s);
    return __bfloat162float(h);
}

// 16 consecutive elements of one row -> wide stores
__device__ __forceinline__ void storeRow(float* p, float4 f0, float4 f1, float4 f2, float4 f3) {
    ((float4*)p)[0] = f0; ((float4*)p)[1] = f1; ((float4*)p)[2] = f2; ((float4*)p)[3] = f3;
}
__device__ __forceinline__ void storeRow(__hip_bfloat16* p, float4 f0, float4 f1, float4 f2, float4 f3) {
    v8s o0, o1;
    o0[0]=f2b(f0.x); o0[1]=f2b(f0.y); o0[2]=f2b(f0.z); o0[3]=f2b(f0.w);
    o0[4]=f2b(f1.x); o0[5]=f2b(f1.y); o0[6]=f2b(f1.z); o0[7]=f2b(f1.w);
    o1[0]=f2b(f2.x); o1[1]=f2b(f2.y); o1[2]=f2b(f2.z); o1[3]=f2b(f2.w);
    o1[4]=f2b(f3.x); o1[5]=f2b(f3.y); o1[6]=f2b(f3.z); o1[7]=f2b(f3.w);
    ((v8s*)p)[0] = o0; ((v8s*)p)[1] = o1;
}

// ---------------------------------------------------------------------------
// MERGED weight prep, one dispatch (see R9 comments).
// ---------------------------------------------------------------------------
__global__ __launch_bounds__(256) void prep_all(
    const float* __restrict__ Wq, const float* __restrict__ gq, const float* __restrict__ betaq,
    const float* __restrict__ Wk, const float* __restrict__ gk, const float* __restrict__ betak,
    const float* __restrict__ bk,
    const float* __restrict__ Wv, const float* __restrict__ gv, const float* __restrict__ betav,
    const float* __restrict__ bv,
    const float* __restrict__ Woff, const float* __restrict__ Wout,
    short* __restrict__ Wq2t, float* __restrict__ bq2,
    short* __restrict__ Wkvt, float* __restrict__ bkv,
    float* __restrict__ Wcomb, float* __restrict__ braw, short* __restrict__ Woutb) {
    __shared__ float sm[272];
    const int bid = blockIdx.x, t = threadIdx.x;

    if (bid < 1536) {
        const float *W, *g, *beta, *bias_in;
        short* Wt; float* b2; int K, n; float scale;
        if (bid < 512)       { W=Wq; g=gq; beta=betaq; bias_in=nullptr; Wt=Wq2t; b2=bq2; K=512; n=bid;        scale=0.125f; }
        else if (bid < 1024) { W=Wk; g=gk; beta=betak; bias_in=bk; Wt=Wkvt;           b2=bkv;       K=256; n=bid-512;  scale=1.f; }
        else                 { W=Wv; g=gv; beta=betav; bias_in=bv; Wt=Wkvt+512*256;   b2=bkv+512;   K=256; n=bid-1024; scale=1.f; }
        float partial = 0.f;
        for (int k = t; k < K; k += 256) {
            float w = W[k * 512 + n];
            Wt[(size_t)n * K + k] = f2b(scale * g[k] * w);
            partial += beta[k] * w;
        }
        sm[t] = partial;
        __syncthreads();
        for (int s = 128; s > 0; s >>= 1) {
            if (t < s) sm[t] += sm[t + s];
            __syncthreads();
        }
        if (t == 0) b2[n] = scale * ((bias_in ? bias_in[n] : 0.f) + sm[0]);
    } else if (bid < 2048) {
        const int k = bid - 1536;
        const int hp = t & 15, jg = t >> 4;
        float p = 0.f;
        for (int j = jg; j < INNER_; j += 16)
            p += Wq[k * INNER_ + j] * Woff[hp * INNER_ + j];
        sm[jg * 17 + hp] = p;
        __syncthreads();
        if (t < 16) {
            float s = 0.f;
            for (int i = 0; i < 16; i++) s += sm[i * 17 + t];
            Wcomb[k * 16 + t] = gq[k] * s;
            braw[k * 16 + t]  = betaq[k] * s;
        }
    } else {
        const int i0 = (bid - 2048) * 1024 + t * 4;
        float4 f = *(const float4*)(Wout + i0);
        v4s o;
        o[0] = f2b(f.x); o[1] = f2b(f.y); o[2] = f2b(f.z); o[3] = f2b(f.w);
        *(v4s*)(Woutb + i0) = o;
    }
}

// bcomb[hp] = sum_k braw[k][hp] + boff[hp]  (deterministic 1-block reduce)
__global__ void bcomb_sum(const float* __restrict__ braw, const float* __restrict__ boff,
                          float* __restrict__ bcomb) {
    __shared__ float sm[272];
    int t = threadIdx.x;
    int hp = t & 15, kg = t >> 4;
    float p = 0.f;
    for (int k = kg; k < 512; k += 16) p += braw[k * 16 + hp];
    sm[kg * 17 + hp] = p;
    __syncthreads();
    if (t < 16) {
        float s = 0.f;
        for (int i = 0; i < 16; i++) s += sm[i * 17 + t];
        bcomb[t] = s + boff[t];
    }
}

// ---------------------------------------------------------------------------
// FUSED single-pass LN + activations + offsets. One wave per 4 rows.
// ---------------------------------------------------------------------------
__global__ __launch_bounds__(256) void norm_fused_kernel(
    const float* __restrict__ x, const float* __restrict__ p,
    const float* __restrict__ Wcomb, const float* __restrict__ bcomb,
    short* __restrict__ Aq, short* __restrict__ Akv,
    float* __restrict__ out_off, int* __restrict__ idx) {
    const int lane = threadIdx.x & 63;
    const int wv   = threadIdx.x >> 6;
    const int m0   = (blockIdx.x * 4 + wv) * 4;   // first of 4 rows
    const int k8   = lane * 8;

    float4 w[8][4];
#pragma unroll
    for (int i = 0; i < 8; i++) {
        const float4* wr = (const float4*)(Wcomb + (size_t)(k8 + i) * 16);
#pragma unroll
        for (int j = 0; j < 4; j++) w[i][j] = wr[j];
    }
    const float bc = bcomb[lane & 15];

    const float* srcb = (lane < 32) ? (x + k8) : (p + k8 - DIM_);

    float4 u0 = ((const float4*)(srcb + (size_t)m0 * DIM_))[0];
    float4 u1 = ((const float4*)(srcb + (size_t)m0 * DIM_))[1];

#pragma unroll
    for (int r = 0; r < 4; r++) {
        const int m = m0 + r;
        float4 n0, n1;
        if (r < 3) {
            n0 = ((const float4*)(srcb + (size_t)(m + 1) * DIM_))[0];
            n1 = ((const float4*)(srcb + (size_t)(m + 1) * DIM_))[1];
        }
        float uv[8] = { u0.x, u0.y, u0.z, u0.w, u1.x, u1.y, u1.z, u1.w };

        float s = 0.f, q2 = 0.f;
#pragma unroll
        for (int i = 0; i < 8; i++) { s += uv[i]; q2 += uv[i] * uv[i]; }
#pragma unroll
        for (int d = 1; d <= 16; d <<= 1) {
            s  += __shfl_xor(s, d);
            q2 += __shfl_xor(q2, d);
        }
        float mean_h = s * (1.f / 256.f);
        float var_h  = q2 * (1.f / 256.f) - mean_h * mean_h;
        float rstd_h = rsqrtf(var_h + 1e-5f);
        float sf  = s  + __shfl_xor(s, 32);
        float q2f = q2 + __shfl_xor(q2, 32);
        float mean_q = sf * (1.f / 512.f);
        float var_q  = q2f * (1.f / 512.f) - mean_q * mean_q;
        float rstd_q = rsqrtf(var_q + 1e-5f);

        v8s okv;
#pragma unroll
        for (int i = 0; i < 8; i++) okv[i] = f2b((uv[i] - mean_h) * rstd_h);
        short* akvdst = Akv + ((lane < 32) ? ((size_t)m * DIM_ + k8)
                                           : ((size_t)(BN_ + m) * DIM_ + k8 - DIM_));
        *(v8s*)akvdst = okv;

        float nv[8];
        v8s oq;
#pragma unroll
        for (int i = 0; i < 8; i++) { nv[i] = (uv[i] - mean_q) * rstd_q; oq[i] = f2b(nv[i]); }
        *(v8s*)(Aq + (size_t)m * INNER_ + k8) = oq;

        float acc[16];
#pragma unroll
        for (int h = 0; h < 16; h++) acc[h] = 0.f;
#pragma unroll
        for (int i = 0; i < 8; i++) {
            float nvi = nv[i];
            acc[0]  += nvi * w[i][0].x;  acc[1]  += nvi * w[i][0].y;
            acc[2]  += nvi * w[i][0].z;  acc[3]  += nvi * w[i][0].w;
            acc[4]  += nvi * w[i][1].x;  acc[5]  += nvi * w[i][1].y;
            acc[6]  += nvi * w[i][1].z;  acc[7]  += nvi * w[i][1].w;
            acc[8]  += nvi * w[i][2].x;  acc[9]  += nvi * w[i][2].y;
            acc[10] += nvi * w[i][2].z;  acc[11] += nvi * w[i][2].w;
            acc[12] += nvi * w[i][3].x;  acc[13] += nvi * w[i][3].y;
            acc[14] += nvi * w[i][3].z;  acc[15] += nvi * w[i][3].w;
        }
        float a8[8];
#pragma unroll
        for (int j = 0; j < 8; j++) {
            float lo = acc[2 * j] + __shfl_xor(acc[2 * j], 1);
            float hi = acc[2 * j + 1] + __shfl_xor(acc[2 * j + 1], 1);
            a8[j] = (lane & 1) ? hi : lo;
        }
        float a4[4];
#pragma unroll
        for (int j = 0; j < 4; j++) {
            float lo = a8[2 * j] + __shfl_xor(a8[2 * j], 2);
            float hi = a8[2 * j + 1] + __shfl_xor(a8[2 * j + 1], 2);
            a4[j] = (lane & 2) ? hi : lo;
        }
        float a2[2];
#pragma unroll
        for (int j = 0; j < 2; j++) {
            float lo = a4[2 * j] + __shfl_xor(a4[2 * j], 4);
            float hi = a4[2 * j + 1] + __shfl_xor(a4[2 * j + 1], 4);
            a2[j] = (lane & 4) ? hi : lo;
        }
        float l1 = a2[0] + __shfl_xor(a2[0], 8);
        float h1 = a2[1] + __shfl_xor(a2[1], 8);
        float a1 = (lane & 8) ? h1 : l1;
        a1 += __shfl_xor(a1, 16);
        a1 += __shfl_xor(a1, 32);

        if (lane < 16) {
            float off = a1 + bc;
            int b = m >> 12, n = m & (N_ - 1);
            int h = lane >> 1, pp = lane & 1;
            out_off[(size_t)((b * H_ + h) * P_ + pp) * N_ + n] = off;
            float f = fminf(fmaxf((float)n + off, 0.f), (float)(2 * N_ - 1));
            idx[((size_t)(b * H_ + h) * N_ + n) * P_ + pp] = (int)f;
        }
        u0 = n0; u1 = n1;
    }
}

// ---------------------------------------------------------------------------
// bf16 MFMA GEMM body: C[.][N] = A[.][K] @ Bt[N][K]^T + bias.
// 128x128 tile, BK=64, 4 waves (2x2), 4x4 frags of 16x16x32 / wave.
//  - XCD swizzle (panel pinned to one XCD).
//  - Register double-buffer: next k-tile loaded into v8s regs DURING current
//    tile's MFMA phase; ds_write next iter. vmcnt drain at the barrier lands
//    ~a full MFMA phase after issue -> load latency hidden.
//  - XOR chunk swizzle: fragment ds_read_b128 conflict-free.
//  - Epilogue: per-wave LDS transpose with INTRA-WAVE sync only
//    (s_waitcnt lgkmcnt(0); wave64 lockstep) -> no inter-wave barriers.
// ---------------------------------------------------------------------------
template <typename OT>
__device__ __forceinline__ void gemm_body(
    short* smem, const short* __restrict__ A, const short* __restrict__ Bt,
    const float* __restrict__ bias, OT* __restrict__ C, int N, int K, int nx, int lin) {
    short* As = smem;
    short* Bs = smem + 128 * 64;
    const int tid  = threadIdx.x;
    const int lane = tid & 63, w = tid >> 6;
    const int wr = w >> 1, wc = w & 1;
    const int lm = lane & 15, g = lane >> 4;

    const int x8 = lin & 7, t = lin >> 3;
    const int bx = t % nx, by = (t / nx) * 8 + x8;
    const int row0 = by * 128, col0 = bx * 128;

    // per-thread staging slots and their global base pointers
    const short* pa[4];
    const short* pb[4];
#pragma unroll
    for (int r = 0; r < 4; r++) {
        int s   = tid + 256 * r;
        int row = s >> 3, kcs = s & 7;
        int kg  = kcs ^ (row & 7);
        pa[r] = A  + (size_t)(row0 + row) * K + kg * 8;
        pb[r] = Bt + (size_t)(col0 + row) * K + kg * 8;
    }

    v4f acc[4][4];
#pragma unroll
    for (int i = 0; i < 4; i++)
#pragma unroll
        for (int j = 0; j < 4; j++) acc[i][j] = (v4f){0.f, 0.f, 0.f, 0.f};

    // prologue: load tile 0 into registers
    v8s ra[4], rb[4];
#pragma unroll
    for (int r = 0; r < 4; r++) { ra[r] = *(const v8s*)pa[r]; rb[r] = *(const v8s*)pb[r]; }

    for (int k0 = 0; k0 < K; k0 += 64) {
        __syncthreads();   // all waves done reading LDS from previous iter
#pragma unroll
        for (int r = 0; r < 4; r++) {
            int s = tid + 256 * r;
            *(v8s*)(As + s * 8) = ra[r];
            *(v8s*)(Bs + s * 8) = rb[r];
        }
        __syncthreads();   // staged tile visible
        if (k0 + 64 < K) { // issue next tile's loads; consumed next iteration
#pragma unroll
            for (int r = 0; r < 4; r++) {
                ra[r] = *(const v8s*)(pa[r] + k0 + 64);
                rb[r] = *(const v8s*)(pb[r] + k0 + 64);
            }
        }
#pragma unroll
        for (int ks = 0; ks < 2; ks++) {
            v8s af[4], bf[4];
#pragma unroll
            for (int i = 0; i < 4; i++) {
                int m   = wr * 64 + i * 16 + lm;
                int sch = m * 8 + ((ks * 4 + g) ^ (m & 7));
                af[i] = *(const v8s*)(As + sch * 8);
            }
#pragma unroll
            for (int j = 0; j < 4; j++) {
                int n   = wc * 64 + j * 16 + lm;
                int sch = n * 8 + ((ks * 4 + g) ^ (n & 7));
                bf[j] = *(const v8s*)(Bs + sch * 8);
            }
#pragma unroll
            for (int i = 0; i < 4; i++)
#pragma unroll
                for (int j = 0; j < 4; j++)
                    acc[i][j] = __builtin_amdgcn_mfma_f32_16x16x32_bf16(af[i], bf[j], acc[i][j], 0, 0, 0);
        }
    }

#pragma unroll
    for (int j = 0; j < 4; j++) {
        int gc = col0 + wc * 64 + j * 16 + lm;
        float bj = bias ? bias[gc] : 0.f;
#pragma unroll
        for (int i = 0; i < 4; i++)
#pragma unroll
            for (int r = 0; r < 4; r++) acc[i][j][r] += bj;
    }

    // epilogue: per-wave 16x64 transpose; intra-wave sync only
    __syncthreads();   // all waves done with As/Bs (ep aliases them)
    float* ep = (float*)smem + w * (16 * 68);
#pragma unroll
    for (int i = 0; i < 4; i++) {
#pragma unroll
        for (int j = 0; j < 4; j++)
#pragma unroll
            for (int r = 0; r < 4; r++)
                ep[(g * 4 + r) * 68 + j * 16 + lm] = acc[i][j][r];
        asm volatile("s_waitcnt lgkmcnt(0)" ::: "memory");  // writes visible (lockstep wave)
        int rr = lane >> 2, cb = (lane & 3) * 16;
        float4 f0 = *(float4*)(ep + rr * 68 + cb + 0);
        float4 f1 = *(float4*)(ep + rr * 68 + cb + 4);
        float4 f2 = *(float4*)(ep + rr * 68 + cb + 8);
        float4 f3 = *(float4*)(ep + rr * 68 + cb + 12);
        asm volatile("s_waitcnt lgkmcnt(0)" ::: "memory");  // reads landed before next i's writes
        int grow = row0 + wr * 64 + i * 16 + rr;
        int gcol = col0 + wc * 64 + cb;
        storeRow(&C[(size_t)grow * N + gcol], f0, f1, f2, f3);
    }
}

// merged q + kv projection GEMMs (independent; block-range dispatch)
__global__ __launch_bounds__(256) void gemm_qkv(
    const short* __restrict__ Aq, const short* __restrict__ Wq2t,
    const float* __restrict__ bq2, __hip_bfloat16* __restrict__ qb,
    const short* __restrict__ Akv, const short* __restrict__ Wkvt,
    const float* __restrict__ bkv, __hip_bfloat16* __restrict__ kvproj) {
    __shared__ short smem[2 * 128 * 64];
    const int bid = blockIdx.x;
    if (bid < 512)
        gemm_body<__hip_bfloat16>(smem, Aq, Wq2t, bq2, qb, 512, 512, 4, bid);
    else
        gemm_body<__hip_bfloat16>(smem, Akv, Wkvt, bkv, kvproj, 1024, 256, 8, bid - 512);
}

// output projection GEMM
__global__ __launch_bounds__(256) void gemm_out(
    const short* __restrict__ A, const short* __restrict__ Bt,
    const float* __restrict__ bias, float* __restrict__ C) {
    __shared__ short smem[2 * 128 * 64];
    const int lin = blockIdx.y * gridDim.x + blockIdx.x;
    gemm_body<float>(smem, A, Bt, bias, C, 256, 512, 2, lin);
}

// ---------------------------------------------------------------------------
// Attention: 16-lane groups, 4 samples/wave. Lane owns 4-elem DH slice.
// kvproj layout [row][1024]: k cols 0-511, v 512+. q pre-scaled by 0.125.
// ---------------------------------------------------------------------------
__global__ __launch_bounds__(256) void attn_kernel(
    const short* __restrict__ qb, const short* __restrict__ kvproj,
    const int* __restrict__ idx, short* __restrict__ attnout) {
    const int lane = threadIdx.x & 63;
    const int wv   = threadIdx.x >> 6;
    const int s    = lane >> 4, c = lane & 15;
    const int n = blockIdx.x * 16 + wv * 4 + s;
    const int h = blockIdx.y, b = blockIdx.z;
    const int m = b * N_ + n;

    v4s qv = *(const v4s*)(qb + (size_t)m * INNER_ + h * DH_ + c * 4);

    const int* ip = idx + ((size_t)(b * H_ + h) * N_ + n) * P_;
    int j0 = ip[0], j1 = ip[1];
    int r0 = b * N_ + j0 + ((j0 >= N_) ? (BN_ - N_) : 0);
    int r1 = b * N_ + j1 + ((j1 >= N_) ? (BN_ - N_) : 0);
    const short* k0p = kvproj + (size_t)r0 * 1024 + h * DH_ + c * 4;
    const short* k1p = kvproj + (size_t)r1 * 1024 + h * DH_ + c * 4;
    v4s k0 = *(const v4s*)k0p, v0 = *(const v4s*)(k0p + 512);
    v4s k1 = *(const v4s*)k1p, v1 = *(const v4s*)(k1p + 512);

    float q0 = b2f(qv[0]), q1 = b2f(qv[1]), q2 = b2f(qv[2]), q3 = b2f(qv[3]);
    float s0 = q0 * b2f(k0[0]) + q1 * b2f(k0[1]) + q2 * b2f(k0[2]) + q3 * b2f(k0[3]);
    float s1 = q0 * b2f(k1[0]) + q1 * b2f(k1[1]) + q2 * b2f(k1[2]) + q3 * b2f(k1[3]);
#pragma unroll
    for (int d = 1; d <= 8; d <<= 1) {
        s0 += __shfl_xor(s0, d);
        s1 += __shfl_xor(s1, d);
    }
    float mx = fmaxf(s0, s1);
    float e0 = __expf(s0 - mx), e1 = __expf(s1 - mx);
    float inv = 1.f / (e0 + e1);
    v4s o;
#pragma unroll
    for (int i = 0; i < 4; i++)
        o[i] = f2b((e0 * b2f(v0[i]) + e1 * b2f(v1[i])) * inv);
    *(v4s*)(attnout + (size_t)m * INNER_ + h * DH_ + c * 4) = o;
}

// ---------------------------------------------------------------------------
extern "C" void kernel_launch(void* const* d_in, const int* in_sizes, int n_in,
                              void* d_out, int out_size, void* d_ws, size_t ws_size,
                              hipStream_t stream) {
    (void)in_sizes; (void)n_in; (void)out_size; (void)ws_size;

    const float* x      = (const float*)d_in[0];
    const float* prevx  = (const float*)d_in[1];
    const float* ln_q_g = (const float*)d_in[2];
    const float* ln_q_b = (const float*)d_in[3];
    const float* ln_k_g = (const float*)d_in[4];
    const float* ln_k_b = (const float*)d_in[5];
    const float* ln_v_g = (const float*)d_in[6];
    const float* ln_v_b = (const float*)d_in[7];
    const float* Wq     = (const float*)d_in[8];
    const float* Wk     = (const float*)d_in[9];
    const float* bk     = (const float*)d_in[10];
    const float* Wv     = (const float*)d_in[11];
    const float* bv     = (const float*)d_in[12];
    const float* Woff   = (const float*)d_in[13];
    const float* boff   = (const float*)d_in[14];
    const float* Wout   = (const float*)d_in[15];
    const float* bout   = (const float*)d_in[16];

    char* cur = (char*)d_ws;
    auto alloc = [&](size_t bytes) { char* p = cur; cur += (bytes + 255) & ~(size_t)255; return p; };
    short* Aq      = (short*)alloc((size_t)BN_ * INNER_ * 2);     // 16 MB
    short* Akv     = (short*)alloc((size_t)KVR_ * DIM_ * 2);      // 16 MB
    short* qb      = (short*)alloc((size_t)BN_ * INNER_ * 2);     // 16 MB
    short* kvproj  = (short*)alloc((size_t)KVR_ * 1024 * 2);      // 64 MB
    short* attnout = (short*)alloc((size_t)BN_ * INNER_ * 2);     // 16 MB
    short* Wq2t    = (short*)alloc(512 * 512 * 2);
    short* Wkvt    = (short*)alloc(1024 * 256 * 2);
    short* Woutb   = (short*)alloc(256 * 512 * 2);
    float* bq2     = (float*)alloc(512 * 4);
    float* bkv     = (float*)alloc(1024 * 4);
    float* Wcomb   = (float*)alloc(512 * 16 * 4);
    float* braw    = (float*)alloc(512 * 16 * 4);
    float* bcomb   = (float*)alloc(16 * 4);
    int*   idxb    = (int*)alloc((size_t)BN_ * 16 * 4);
    // total ~130 MB

    float* out_main = (float*)d_out;                      // (B,N,DIM)
    float* out_off  = out_main + (size_t)BN_ * DIM_;      // (B,H,P,N)

    // 1) merged weight prep + composed offset weights
    prep_all<<<2176, 256, 0, stream>>>(Wq, ln_q_g, ln_q_b,
                                       Wk, ln_k_g, ln_k_b, bk,
                                       Wv, ln_v_g, ln_v_b, bv,
                                       Woff, Wout,
                                       Wq2t, bq2, Wkvt, bkv, Wcomb, braw, Woutb);
    bcomb_sum<<<1, 256, 0, stream>>>(braw, boff, bcomb);

    // 2) single-pass fused LN + activations + offsets + indices (4 rows/wave)
    norm_fused_kernel<<<BN_ / 16, 256, 0, stream>>>(x, prevx, Wcomb, bcomb,
                                                    Aq, Akv, out_off, idxb);

    // 3) q + kv projections, one dispatch
    gemm_qkv<<<2560, 256, 0, stream>>>(Aq, Wq2t, bq2, (__hip_bfloat16*)qb,
                                       Akv, Wkvt, bkv, (__hip_bfloat16*)kvproj);

    // 4) gather + softmax(P=2) + weighted sum (16-lane groups, 4 samples/wave)
    dim3 ga(N_ / 16, H_, B_);
    attn_kernel<<<ga, 256, 0, stream>>>(qb, kvproj, idxb, attnout);

    // 5) output projection
    gemm_out<<<dim3(2, 128), 256, 0, stream>>>(attnout, Woutb, bout, out_main);
}

// Round 11
// 216.068 us; speedup vs baseline: 3.2823x; 1.0211x over previous
//
#include <hip/hip_runtime.h>
#include <hip/hip_bf16.h>
#include <math.h>

#define B_    4
#define N_    4096
#define DIM_  256
#define H_    8
#define DH_   64
#define P_    2
#define INNER_ 512
#define BN_   (B_ * N_)      // 16384 rows for q/out
#define KVR_  (2 * BN_)      // 32768 rows for k/v

typedef short v8s  __attribute__((ext_vector_type(8)));
typedef short v4s  __attribute__((ext_vector_type(4)));
typedef float v4f  __attribute__((ext_vector_type(4)));

__device__ __forceinline__ short f2b(float x) {
    __hip_bfloat16 h = __float2bfloat16(x);
    return *reinterpret_cast<short*>(&h);
}
__device__ __forceinline__ float b2f(short s) {
    __hip_bfloat16 h = *reinterpret_cast<__hip_bfloat16*>(&s);
    return __bfloat162float(h);
}

__device__ __forceinline__ void async16(const void* g, void* l) {
    __builtin_amdgcn_global_load_lds(
        (const __attribute__((address_space(1))) void*)g,
        (__attribute__((address_space(3))) void*)l, 16, 0, 0);
}

// 16 consecutive elements of one row -> wide stores
__device__ __forceinline__ void storeRow(float* p, float4 f0, float4 f1, float4 f2, float4 f3) {
    ((float4*)p)[0] = f0; ((float4*)p)[1] = f1; ((float4*)p)[2] = f2; ((float4*)p)[3] = f3;
}
__device__ __forceinline__ void storeRow(__hip_bfloat16* p, float4 f0, float4 f1, float4 f2, float4 f3) {
    v8s o0, o1;
    o0[0]=f2b(f0.x); o0[1]=f2b(f0.y); o0[2]=f2b(f0.z); o0[3]=f2b(f0.w);
    o0[4]=f2b(f1.x); o0[5]=f2b(f1.y); o0[6]=f2b(f1.z); o0[7]=f2b(f1.w);
    o1[0]=f2b(f2.x); o1[1]=f2b(f2.y); o1[2]=f2b(f2.z); o1[3]=f2b(f2.w);
    o1[4]=f2b(f3.x); o1[5]=f2b(f3.y); o1[6]=f2b(f3.z); o1[7]=f2b(f3.w);
    ((v8s*)p)[0] = o0; ((v8s*)p)[1] = o1;
}

// ---------------------------------------------------------------------------
// MERGED weight prep, one dispatch (see R9 comments).
// ---------------------------------------------------------------------------
__global__ __launch_bounds__(256) void prep_all(
    const float* __restrict__ Wq, const float* __restrict__ gq, const float* __restrict__ betaq,
    const float* __restrict__ Wk, const float* __restrict__ gk, const float* __restrict__ betak,
    const float* __restrict__ bk,
    const float* __restrict__ Wv, const float* __restrict__ gv, const float* __restrict__ betav,
    const float* __restrict__ bv,
    const float* __restrict__ Woff, const float* __restrict__ Wout,
    short* __restrict__ Wq2t, float* __restrict__ bq2,
    short* __restrict__ Wkvt, float* __restrict__ bkv,
    float* __restrict__ Wcomb, float* __restrict__ braw, short* __restrict__ Woutb) {
    __shared__ float sm[272];
    const int bid = blockIdx.x, t = threadIdx.x;

    if (bid < 1536) {
        const float *W, *g, *beta, *bias_in;
        short* Wt; float* b2; int K, n; float scale;
        if (bid < 512)       { W=Wq; g=gq; beta=betaq; bias_in=nullptr; Wt=Wq2t; b2=bq2; K=512; n=bid;        scale=0.125f; }
        else if (bid < 1024) { W=Wk; g=gk; beta=betak; bias_in=bk; Wt=Wkvt;           b2=bkv;       K=256; n=bid-512;  scale=1.f; }
        else                 { W=Wv; g=gv; beta=betav; bias_in=bv; Wt=Wkvt+512*256;   b2=bkv+512;   K=256; n=bid-1024; scale=1.f; }
        float partial = 0.f;
        for (int k = t; k < K; k += 256) {
            float w = W[k * 512 + n];
            Wt[(size_t)n * K + k] = f2b(scale * g[k] * w);
            partial += beta[k] * w;
        }
        sm[t] = partial;
        __syncthreads();
        for (int s = 128; s > 0; s >>= 1) {
            if (t < s) sm[t] += sm[t + s];
            __syncthreads();
        }
        if (t == 0) b2[n] = scale * ((bias_in ? bias_in[n] : 0.f) + sm[0]);
    } else if (bid < 2048) {
        const int k = bid - 1536;
        const int hp = t & 15, jg = t >> 4;
        float p = 0.f;
        for (int j = jg; j < INNER_; j += 16)
            p += Wq[k * INNER_ + j] * Woff[hp * INNER_ + j];
        sm[jg * 17 + hp] = p;
        __syncthreads();
        if (t < 16) {
            float s = 0.f;
            for (int i = 0; i < 16; i++) s += sm[i * 17 + t];
            Wcomb[k * 16 + t] = gq[k] * s;
            braw[k * 16 + t]  = betaq[k] * s;
        }
    } else {
        const int i0 = (bid - 2048) * 1024 + t * 4;
        float4 f = *(const float4*)(Wout + i0);
        v4s o;
        o[0] = f2b(f.x); o[1] = f2b(f.y); o[2] = f2b(f.z); o[3] = f2b(f.w);
        *(v4s*)(Woutb + i0) = o;
    }
}

// bcomb[hp] = sum_k braw[k][hp] + boff[hp]  (deterministic 1-block reduce)
__global__ void bcomb_sum(const float* __restrict__ braw, const float* __restrict__ boff,
                          float* __restrict__ bcomb) {
    __shared__ float sm[272];
    int t = threadIdx.x;
    int hp = t & 15, kg = t >> 4;
    float p = 0.f;
    for (int k = kg; k < 512; k += 16) p += braw[k * 16 + hp];
    sm[kg * 17 + hp] = p;
    __syncthreads();
    if (t < 16) {
        float s = 0.f;
        for (int i = 0; i < 16; i++) s += sm[i * 17 + t];
        bcomb[t] = s + boff[t];
    }
}

// ---------------------------------------------------------------------------
// FUSED single-pass LN + activations + offsets. One wave per 4 rows.
// ---------------------------------------------------------------------------
__global__ __launch_bounds__(256) void norm_fused_kernel(
    const float* __restrict__ x, const float* __restrict__ p,
    const float* __restrict__ Wcomb, const float* __restrict__ bcomb,
    short* __restrict__ Aq, short* __restrict__ Akv,
    float* __restrict__ out_off, int* __restrict__ idx) {
    const int lane = threadIdx.x & 63;
    const int wv   = threadIdx.x >> 6;
    const int m0   = (blockIdx.x * 4 + wv) * 4;   // first of 4 rows
    const int k8   = lane * 8;

    float4 w[8][4];
#pragma unroll
    for (int i = 0; i < 8; i++) {
        const float4* wr = (const float4*)(Wcomb + (size_t)(k8 + i) * 16);
#pragma unroll
        for (int j = 0; j < 4; j++) w[i][j] = wr[j];
    }
    const float bc = bcomb[lane & 15];

    const float* srcb = (lane < 32) ? (x + k8) : (p + k8 - DIM_);

    float4 u0 = ((const float4*)(srcb + (size_t)m0 * DIM_))[0];
    float4 u1 = ((const float4*)(srcb + (size_t)m0 * DIM_))[1];

#pragma unroll
    for (int r = 0; r < 4; r++) {
        const int m = m0 + r;
        float4 n0, n1;
        if (r < 3) {
            n0 = ((const float4*)(srcb + (size_t)(m + 1) * DIM_))[0];
            n1 = ((const float4*)(srcb + (size_t)(m + 1) * DIM_))[1];
        }
        float uv[8] = { u0.x, u0.y, u0.z, u0.w, u1.x, u1.y, u1.z, u1.w };

        float s = 0.f, q2 = 0.f;
#pragma unroll
        for (int i = 0; i < 8; i++) { s += uv[i]; q2 += uv[i] * uv[i]; }
#pragma unroll
        for (int d = 1; d <= 16; d <<= 1) {
            s  += __shfl_xor(s, d);
            q2 += __shfl_xor(q2, d);
        }
        float mean_h = s * (1.f / 256.f);
        float var_h  = q2 * (1.f / 256.f) - mean_h * mean_h;
        float rstd_h = rsqrtf(var_h + 1e-5f);
        float sf  = s  + __shfl_xor(s, 32);
        float q2f = q2 + __shfl_xor(q2, 32);
        float mean_q = sf * (1.f / 512.f);
        float var_q  = q2f * (1.f / 512.f) - mean_q * mean_q;
        float rstd_q = rsqrtf(var_q + 1e-5f);

        v8s okv;
#pragma unroll
        for (int i = 0; i < 8; i++) okv[i] = f2b((uv[i] - mean_h) * rstd_h);
        short* akvdst = Akv + ((lane < 32) ? ((size_t)m * DIM_ + k8)
                                           : ((size_t)(BN_ + m) * DIM_ + k8 - DIM_));
        *(v8s*)akvdst = okv;

        float nv[8];
        v8s oq;
#pragma unroll
        for (int i = 0; i < 8; i++) { nv[i] = (uv[i] - mean_q) * rstd_q; oq[i] = f2b(nv[i]); }
        *(v8s*)(Aq + (size_t)m * INNER_ + k8) = oq;

        float acc[16];
#pragma unroll
        for (int h = 0; h < 16; h++) acc[h] = 0.f;
#pragma unroll
        for (int i = 0; i < 8; i++) {
            float nvi = nv[i];
            acc[0]  += nvi * w[i][0].x;  acc[1]  += nvi * w[i][0].y;
            acc[2]  += nvi * w[i][0].z;  acc[3]  += nvi * w[i][0].w;
            acc[4]  += nvi * w[i][1].x;  acc[5]  += nvi * w[i][1].y;
            acc[6]  += nvi * w[i][1].z;  acc[7]  += nvi * w[i][1].w;
            acc[8]  += nvi * w[i][2].x;  acc[9]  += nvi * w[i][2].y;
            acc[10] += nvi * w[i][2].z;  acc[11] += nvi * w[i][2].w;
            acc[12] += nvi * w[i][3].x;  acc[13] += nvi * w[i][3].y;
            acc[14] += nvi * w[i][3].z;  acc[15] += nvi * w[i][3].w;
        }
        float a8[8];
#pragma unroll
        for (int j = 0; j < 8; j++) {
            float lo = acc[2 * j] + __shfl_xor(acc[2 * j], 1);
            float hi = acc[2 * j + 1] + __shfl_xor(acc[2 * j + 1], 1);
            a8[j] = (lane & 1) ? hi : lo;
        }
        float a4[4];
#pragma unroll
        for (int j = 0; j < 4; j++) {
            float lo = a8[2 * j] + __shfl_xor(a8[2 * j], 2);
            float hi = a8[2 * j + 1] + __shfl_xor(a8[2 * j + 1], 2);
            a4[j] = (lane & 2) ? hi : lo;
        }
        float a2[2];
#pragma unroll
        for (int j = 0; j < 2; j++) {
            float lo = a4[2 * j] + __shfl_xor(a4[2 * j], 4);
            float hi = a4[2 * j + 1] + __shfl_xor(a4[2 * j + 1], 4);
            a2[j] = (lane & 4) ? hi : lo;
        }
        float l1 = a2[0] + __shfl_xor(a2[0], 8);
        float h1 = a2[1] + __shfl_xor(a2[1], 8);
        float a1 = (lane & 8) ? h1 : l1;
        a1 += __shfl_xor(a1, 16);
        a1 += __shfl_xor(a1, 32);

        if (lane < 16) {
            float off = a1 + bc;
            int b = m >> 12, n = m & (N_ - 1);
            int h = lane >> 1, pp = lane & 1;
            out_off[(size_t)((b * H_ + h) * P_ + pp) * N_ + n] = off;
            float f = fminf(fmaxf((float)n + off, 0.f), (float)(2 * N_ - 1));
            idx[((size_t)(b * H_ + h) * N_ + n) * P_ + pp] = (int)f;
        }
        u0 = n0; u1 = n1;
    }
}

// ---------------------------------------------------------------------------
// bf16 MFMA GEMM body: C[.][N] = A[.][K] @ Bt[N][K]^T + bias.
// 128x128 tile, BK=64, 4 waves (2x2), 4x4 frags of 16x16x32 / wave.
//  - XCD swizzle (panel pinned to one XCD).
//  - global_load_lds width=16 async staging (R9 structure; R10's register
//    double-buffer REGRESSED 49->60 us: MFMA phase << load latency, extra
//    VALU + VGPR cost -- do not reintroduce).
//  - XOR chunk swizzle: fragment ds_read_b128 conflict-free.
//  - Epilogue: per-wave LDS transpose with INTRA-WAVE sync only.
// ---------------------------------------------------------------------------
template <typename OT>
__device__ __forceinline__ void gemm_body(
    short* smem, const short* __restrict__ A, const short* __restrict__ Bt,
    const float* __restrict__ bias, OT* __restrict__ C, int N, int K, int nx, int lin) {
    short* As = smem;
    short* Bs = smem + 128 * 64;
    const int tid  = threadIdx.x;
    const int lane = tid & 63, w = tid >> 6;
    const int wr = w >> 1, wc = w & 1;
    const int lm = lane & 15, g = lane >> 4;

    const int x8 = lin & 7, t = lin >> 3;
    const int bx = t % nx, by = (t / nx) * 8 + x8;
    const int row0 = by * 128, col0 = bx * 128;

    // per-thread staging slots and their global base pointers (hoisted)
    const short* pa[4];
    const short* pb[4];
#pragma unroll
    for (int r = 0; r < 4; r++) {
        int s   = tid + 256 * r;
        int row = s >> 3, kcs = s & 7;
        int kg  = kcs ^ (row & 7);
        pa[r] = A  + (size_t)(row0 + row) * K + kg * 8;
        pb[r] = Bt + (size_t)(col0 + row) * K + kg * 8;
    }

    v4f acc[4][4];
#pragma unroll
    for (int i = 0; i < 4; i++)
#pragma unroll
        for (int j = 0; j < 4; j++) acc[i][j] = (v4f){0.f, 0.f, 0.f, 0.f};

    for (int k0 = 0; k0 < K; k0 += 64) {
        __syncthreads();   // all waves done reading LDS from previous iter
#pragma unroll
        for (int r = 0; r < 4; r++) {
            int s = tid + 256 * r;
            async16(pa[r] + k0, (char*)As + s * 16);
            async16(pb[r] + k0, (char*)Bs + s * 16);
        }
        __syncthreads();   // drains vmcnt -> LDS valid
#pragma unroll
        for (int ks = 0; ks < 2; ks++) {
            v8s af[4], bf[4];
#pragma unroll
            for (int i = 0; i < 4; i++) {
                int m   = wr * 64 + i * 16 + lm;
                int sch = m * 8 + ((ks * 4 + g) ^ (m & 7));
                af[i] = *(const v8s*)(As + sch * 8);
            }
#pragma unroll
            for (int j = 0; j < 4; j++) {
                int n   = wc * 64 + j * 16 + lm;
                int sch = n * 8 + ((ks * 4 + g) ^ (n & 7));
                bf[j] = *(const v8s*)(Bs + sch * 8);
            }
#pragma unroll
            for (int i = 0; i < 4; i++)
#pragma unroll
                for (int j = 0; j < 4; j++)
                    acc[i][j] = __builtin_amdgcn_mfma_f32_16x16x32_bf16(af[i], bf[j], acc[i][j], 0, 0, 0);
        }
    }

#pragma unroll
    for (int j = 0; j < 4; j++) {
        int gc = col0 + wc * 64 + j * 16 + lm;
        float bj = bias ? bias[gc] : 0.f;
#pragma unroll
        for (int i = 0; i < 4; i++)
#pragma unroll
            for (int r = 0; r < 4; r++) acc[i][j][r] += bj;
    }

    // epilogue: per-wave 16x64 transpose; intra-wave sync only
    __syncthreads();   // all waves done with As/Bs (ep aliases them)
    float* ep = (float*)smem + w * (16 * 68);
#pragma unroll
    for (int i = 0; i < 4; i++) {
#pragma unroll
        for (int j = 0; j < 4; j++)
#pragma unroll
            for (int r = 0; r < 4; r++)
                ep[(g * 4 + r) * 68 + j * 16 + lm] = acc[i][j][r];
        asm volatile("s_waitcnt lgkmcnt(0)" ::: "memory");  // writes visible (lockstep wave)
        int rr = lane >> 2, cb = (lane & 3) * 16;
        float4 f0 = *(float4*)(ep + rr * 68 + cb + 0);
        float4 f1 = *(float4*)(ep + rr * 68 + cb + 4);
        float4 f2 = *(float4*)(ep + rr * 68 + cb + 8);
        float4 f3 = *(float4*)(ep + rr * 68 + cb + 12);
        asm volatile("s_waitcnt lgkmcnt(0)" ::: "memory");  // reads landed before next i's writes
        int grow = row0 + wr * 64 + i * 16 + rr;
        int gcol = col0 + wc * 64 + cb;
        storeRow(&C[(size_t)grow * N + gcol], f0, f1, f2, f3);
    }
}

// merged q + kv projection GEMMs (independent; block-range dispatch)
__global__ __launch_bounds__(256) void gemm_qkv(
    const short* __restrict__ Aq, const short* __restrict__ Wq2t,
    const float* __restrict__ bq2, __hip_bfloat16* __restrict__ qb,
    const short* __restrict__ Akv, const short* __restrict__ Wkvt,
    const float* __restrict__ bkv, __hip_bfloat16* __restrict__ kvproj) {
    __shared__ short smem[2 * 128 * 64];
    const int bid = blockIdx.x;
    if (bid < 512)
        gemm_body<__hip_bfloat16>(smem, Aq, Wq2t, bq2, qb, 512, 512, 4, bid);
    else
        gemm_body<__hip_bfloat16>(smem, Akv, Wkvt, bkv, kvproj, 1024, 256, 8, bid - 512);
}

// output projection GEMM
__global__ __launch_bounds__(256) void gemm_out(
    const short* __restrict__ A, const short* __restrict__ Bt,
    const float* __restrict__ bias, float* __restrict__ C) {
    __shared__ short smem[2 * 128 * 64];
    const int lin = blockIdx.y * gridDim.x + blockIdx.x;
    gemm_body<float>(smem, A, Bt, bias, C, 256, 512, 2, lin);
}

// ---------------------------------------------------------------------------
// Attention: 16-lane groups, 4 samples/wave. Lane owns 4-elem DH slice.
// kvproj layout [row][1024]: k cols 0-511, v 512+. q pre-scaled by 0.125.
// ---------------------------------------------------------------------------
__global__ __launch_bounds__(256) void attn_kernel(
    const short* __restrict__ qb, const short* __restrict__ kvproj,
    const int* __restrict__ idx, short* __restrict__ attnout) {
    const int lane = threadIdx.x & 63;
    const int wv   = threadIdx.x >> 6;
    const int s    = lane >> 4, c = lane & 15;
    const int n = blockIdx.x * 16 + wv * 4 + s;
    const int h = blockIdx.y, b = blockIdx.z;
    const int m = b * N_ + n;

    v4s qv = *(const v4s*)(qb + (size_t)m * INNER_ + h * DH_ + c * 4);

    const int* ip = idx + ((size_t)(b * H_ + h) * N_ + n) * P_;
    int j0 = ip[0], j1 = ip[1];
    int r0 = b * N_ + j0 + ((j0 >= N_) ? (BN_ - N_) : 0);
    int r1 = b * N_ + j1 + ((j1 >= N_) ? (BN_ - N_) : 0);
    const short* k0p = kvproj + (size_t)r0 * 1024 + h * DH_ + c * 4;
    const short* k1p = kvproj + (size_t)r1 * 1024 + h * DH_ + c * 4;
    v4s k0 = *(const v4s*)k0p, v0 = *(const v4s*)(k0p + 512);
    v4s k1 = *(const v4s*)k1p, v1 = *(const v4s*)(k1p + 512);

    float q0 = b2f(qv[0]), q1 = b2f(qv[1]), q2 = b2f(qv[2]), q3 = b2f(qv[3]);
    float s0 = q0 * b2f(k0[0]) + q1 * b2f(k0[1]) + q2 * b2f(k0[2]) + q3 * b2f(k0[3]);
    float s1 = q0 * b2f(k1[0]) + q1 * b2f(k1[1]) + q2 * b2f(k1[2]) + q3 * b2f(k1[3]);
#pragma unroll
    for (int d = 1; d <= 8; d <<= 1) {
        s0 += __shfl_xor(s0, d);
        s1 += __shfl_xor(s1, d);
    }
    float mx = fmaxf(s0, s1);
    float e0 = __expf(s0 - mx), e1 = __expf(s1 - mx);
    float inv = 1.f / (e0 + e1);
    v4s o;
#pragma unroll
    for (int i = 0; i < 4; i++)
        o[i] = f2b((e0 * b2f(v0[i]) + e1 * b2f(v1[i])) * inv);
    *(v4s*)(attnout + (size_t)m * INNER_ + h * DH_ + c * 4) = o;
}

// ---------------------------------------------------------------------------
extern "C" void kernel_launch(void* const* d_in, const int* in_sizes, int n_in,
                              void* d_out, int out_size, void* d_ws, size_t ws_size,
                              hipStream_t stream) {
    (void)in_sizes; (void)n_in; (void)out_size; (void)ws_size;

    const float* x      = (const float*)d_in[0];
    const float* prevx  = (const float*)d_in[1];
    const float* ln_q_g = (const float*)d_in[2];
    const float* ln_q_b = (const float*)d_in[3];
    const float* ln_k_g = (const float*)d_in[4];
    const float* ln_k_b = (const float*)d_in[5];
    const float* ln_v_g = (const float*)d_in[6];
    const float* ln_v_b = (const float*)d_in[7];
    const float* Wq     = (const float*)d_in[8];
    const float* Wk     = (const float*)d_in[9];
    const float* bk     = (const float*)d_in[10];
    const float* Wv     = (const float*)d_in[11];
    const float* bv     = (const float*)d_in[12];
    const float* Woff   = (const float*)d_in[13];
    const float* boff   = (const float*)d_in[14];
    const float* Wout   = (const float*)d_in[15];
    const float* bout   = (const float*)d_in[16];

    char* cur = (char*)d_ws;
    auto alloc = [&](size_t bytes) { char* p = cur; cur += (bytes + 255) & ~(size_t)255; return p; };
    short* Aq      = (short*)alloc((size_t)BN_ * INNER_ * 2);     // 16 MB
    short* Akv     = (short*)alloc((size_t)KVR_ * DIM_ * 2);      // 16 MB
    short* qb      = (short*)alloc((size_t)BN_ * INNER_ * 2);     // 16 MB
    short* kvproj  = (short*)alloc((size_t)KVR_ * 1024 * 2);      // 64 MB
    short* attnout = (short*)alloc((size_t)BN_ * INNER_ * 2);     // 16 MB
    short* Wq2t    = (short*)alloc(512 * 512 * 2);
    short* Wkvt    = (short*)alloc(1024 * 256 * 2);
    short* Woutb   = (short*)alloc(256 * 512 * 2);
    float* bq2     = (float*)alloc(512 * 4);
    float* bkv     = (float*)alloc(1024 * 4);
    float* Wcomb   = (float*)alloc(512 * 16 * 4);
    float* braw    = (float*)alloc(512 * 16 * 4);
    float* bcomb   = (float*)alloc(16 * 4);
    int*   idxb    = (int*)alloc((size_t)BN_ * 16 * 4);
    // total ~130 MB

    float* out_main = (float*)d_out;                      // (B,N,DIM)
    float* out_off  = out_main + (size_t)BN_ * DIM_;      // (B,H,P,N)

    // 1) merged weight prep + composed offset weights
    prep_all<<<2176, 256, 0, stream>>>(Wq, ln_q_g, ln_q_b,
                                       Wk, ln_k_g, ln_k_b, bk,
                                       Wv, ln_v_g, ln_v_b, bv,
                                       Woff, Wout,
                                       Wq2t, bq2, Wkvt, bkv, Wcomb, braw, Woutb);
    bcomb_sum<<<1, 256, 0, stream>>>(braw, boff, bcomb);

    // 2) single-pass fused LN + activations + offsets + indices (4 rows/wave)
    norm_fused_kernel<<<BN_ / 16, 256, 0, stream>>>(x, prevx, Wcomb, bcomb,
                                                    Aq, Akv, out_off, idxb);

    // 3) q + kv projections, one dispatch
    gemm_qkv<<<2560, 256, 0, stream>>>(Aq, Wq2t, bq2, (__hip_bfloat16*)qb,
                                       Akv, Wkvt, bkv, (__hip_bfloat16*)kvproj);

    // 4) gather + softmax(P=2) + weighted sum (16-lane groups, 4 samples/wave)
    dim3 ga(N_ / 16, H_, B_);
    attn_kernel<<<ga, 256, 0, stream>>>(qb, kvproj, idxb, attnout);

    // 5) output projection
    gemm_out<<<dim3(2, 128), 256, 0, stream>>>(attnout, Woutb, bout, out_main);
}